// Round 1
// baseline (9217.544 us; speedup 1.0000x reference)
//
#include <hip/hip_runtime.h>
#include <math.h>

#define BB 16
#define TT 256
#define DIN 384
#define DD 512
#define LL 6
#define HH 8
#define HD 64
#define PP 64
#define SS 10
#define BT (BB*TT)   // 4096

enum { ACT_NONE=0, ACT_RELU=1, ACT_TANH=2, ACT_SILU=3 };

// ---------------- generic tiled SGEMM: C = act(A @ W + bias), optional += ----------------
// A: M x K (lda), W: K x N row-major, C: M x ldc.
// Row-shift masking for causal conv: A-row for output row r is (r - shift),
// valid iff (r % TT) >= shift (keeps batches independent). shift=0 => normal.
__global__ __launch_bounds__(256) void gemm_kernel(
    const float* __restrict__ A, int lda,
    const float* __restrict__ W,
    const float* __restrict__ bias,
    float* __restrict__ C, int ldc,
    int M, int N, int K, int shift, int accum, int act)
{
    __shared__ float As[16][68];
    __shared__ float Ws[16][64];
    const int tid = threadIdx.x;
    const int tx = tid & 15, ty = tid >> 4;
    const int row0 = blockIdx.y * 64, col0 = blockIdx.x * 64;
    float acc[4][4] = {};
    for (int k0 = 0; k0 < K; k0 += 16) {
        #pragma unroll
        for (int q = 0; q < 4; ++q) {
            int e = tid + q * 256;
            int r = e >> 4, c = e & 15;          // A tile: 64 rows x 16 cols
            int grow = row0 + r;
            float av = 0.f;
            if (grow < M && (grow % TT) >= shift)
                av = A[(size_t)(grow - shift) * lda + k0 + c];
            As[c][r] = av;
            int wr = e >> 6, wc = e & 63;        // W tile: 16 rows x 64 cols
            int gcol = col0 + wc;
            Ws[wr][wc] = (gcol < N) ? W[(size_t)(k0 + wr) * N + gcol] : 0.f;
        }
        __syncthreads();
        #pragma unroll
        for (int kk = 0; kk < 16; ++kk) {
            float a[4], b[4];
            #pragma unroll
            for (int u = 0; u < 4; ++u) { a[u] = As[kk][ty*4+u]; b[u] = Ws[kk][tx*4+u]; }
            #pragma unroll
            for (int u = 0; u < 4; ++u)
                #pragma unroll
                for (int w = 0; w < 4; ++w) acc[u][w] += a[u] * b[w];
        }
        __syncthreads();
    }
    #pragma unroll
    for (int u = 0; u < 4; ++u) {
        int r = row0 + ty*4 + u;
        if (r >= M) continue;
        #pragma unroll
        for (int w = 0; w < 4; ++w) {
            int c = col0 + tx*4 + w;
            if (c >= N) continue;
            float v = acc[u][w] + (bias ? bias[c] : 0.f);
            if (act == ACT_RELU)      v = fmaxf(v, 0.f);
            else if (act == ACT_TANH) v = tanhf(v);
            else if (act == ACT_SILU) v = v / (1.f + expf(-v));
            size_t o = (size_t)r * ldc + c;
            if (accum) C[o] += v; else C[o] = v;
        }
    }
}

// ---------------- per-head squared norms: outn[(b*H+h)*T+t] = sum_d x[b,t,h*64+d]^2 ----------------
__global__ __launch_bounds__(256) void sqnorm_kernel(const float* __restrict__ x, float* __restrict__ outn)
{
    int lane = threadIdx.x & 63, wid = threadIdx.x >> 6;
    int row = blockIdx.x * 4 + wid;            // over B*H*T
    int t = row & 255; int bh = row >> 8; int b = bh >> 3, hh = bh & 7;
    float v = x[((size_t)b * TT + t) * DD + hh * HD + lane];
    float s = v * v;
    #pragma unroll
    for (int off = 32; off; off >>= 1) s += __shfl_xor(s, off);
    if (lane == 0) outn[row] = s;
}

// ---------------- batched S = q . k^T per (b,h): 64x64 tile, K=64 ----------------
__global__ __launch_bounds__(256) void qk_kernel(const float* __restrict__ q, const float* __restrict__ k,
                                                 float* __restrict__ outp)
{
    int bh = blockIdx.z; int b = bh >> 3, hh = bh & 7;
    const float* qb = q + (size_t)b * TT * DD + hh * HD;
    const float* kb = k + (size_t)b * TT * DD + hh * HD;
    float* ob = outp + (size_t)bh * TT * TT;
    int i0 = blockIdx.y * 64, j0 = blockIdx.x * 64;
    __shared__ float Qs[64][65];
    __shared__ float Ks[64][65];
    int tid = threadIdx.x;
    for (int e = tid; e < 64 * 64; e += 256) {
        int r = e >> 6, c = e & 63;
        Qs[r][c] = qb[(size_t)(i0 + r) * DD + c];
        Ks[r][c] = kb[(size_t)(j0 + r) * DD + c];
    }
    __syncthreads();
    int tx = tid & 15, ty = tid >> 4;
    float acc[4][4] = {};
    #pragma unroll 8
    for (int d = 0; d < 64; ++d) {
        float a[4], b2[4];
        #pragma unroll
        for (int u = 0; u < 4; ++u) { a[u] = Qs[ty*4+u][d]; b2[u] = Ks[tx*4+u][d]; }
        #pragma unroll
        for (int u = 0; u < 4; ++u)
            #pragma unroll
            for (int w = 0; w < 4; ++w) acc[u][w] += a[u] * b2[w];
    }
    #pragma unroll
    for (int u = 0; u < 4; ++u)
        #pragma unroll
        for (int w = 0; w < 4; ++w)
            ob[(size_t)(i0 + ty*4 + u) * TT + j0 + tx*4 + w] = acc[u][w];
}

// ---------------- hyperbolic distance + softmax, in place on qk logits ----------------
__global__ __launch_bounds__(256) void attn_softmax_kernel(float* __restrict__ at,
                                                           const float* __restrict__ qn,
                                                           const float* __restrict__ kn,
                                                           const float* __restrict__ curv)
{
    int lane = threadIdx.x & 63, wid = threadIdx.x >> 6;
    int row = blockIdx.x * 4 + wid;            // over B*H*T
    int i = row & 255; int bh = row >> 8; int hh = bh & 7;
    float c = fabsf(curv[hh]) + 1e-8f;
    float inv_sqrt_c = 1.f / sqrtf(c);
    float qni = qn[row];
    float* srow = at + (size_t)bh * TT * TT + (size_t)i * TT;
    const float* knr = kn + (size_t)bh * TT;
    float logit[4];
    float mx = -1e30f;
    #pragma unroll
    for (int u = 0; u < 4; ++u) {
        int j = lane + u * 64;
        float s = srow[j];
        float knj = knr[j];
        float d2 = fmaxf(qni + knj - 2.f * s, 0.f);
        float denom = fmaxf((1.f - c * qni) * (1.f - c * knj), 1e-5f);
        float arg = fmaxf(1.f + (2.f * c * d2) / denom, 1.00001f);
        float dist = logf(arg + sqrtf((arg - 1.f) * (arg + 1.f))) * inv_sqrt_c;
        logit[u] = -dist;
        mx = fmaxf(mx, logit[u]);
    }
    #pragma unroll
    for (int off = 32; off; off >>= 1) mx = fmaxf(mx, __shfl_xor(mx, off));
    float e[4]; float sum = 0.f;
    #pragma unroll
    for (int u = 0; u < 4; ++u) { e[u] = expf(logit[u] - mx); sum += e[u]; }
    #pragma unroll
    for (int off = 32; off; off >>= 1) sum += __shfl_xor(sum, off);
    float inv = 1.f / sum;
    #pragma unroll
    for (int u = 0; u < 4; ++u) srow[lane + u * 64] = e[u] * inv;
}

// ---------------- batched geomv = attn @ v per (b,h): 64 rows x 64 cols, K=256 ----------------
__global__ __launch_bounds__(256) void pv_kernel(const float* __restrict__ at, const float* __restrict__ v,
                                                 float* __restrict__ outp)
{
    int bh = blockIdx.y; int b = bh >> 3, hh = bh & 7;
    int i0 = blockIdx.x * 64;
    const float* ab = at + (size_t)bh * TT * TT;
    const float* vb = v + (size_t)b * TT * DD + hh * HD;
    float* ob = outp + (size_t)b * TT * DD + hh * HD;
    __shared__ float As[64][65];
    __shared__ float Vs[64][65];
    int tid = threadIdx.x, tx = tid & 15, ty = tid >> 4;
    float acc[4][4] = {};
    for (int j0 = 0; j0 < TT; j0 += 64) {
        for (int e = tid; e < 64 * 64; e += 256) {
            int r = e >> 6, c = e & 63;
            As[r][c] = ab[(size_t)(i0 + r) * TT + j0 + c];
            Vs[r][c] = vb[(size_t)(j0 + r) * DD + c];
        }
        __syncthreads();
        #pragma unroll 8
        for (int kk = 0; kk < 64; ++kk) {
            float a[4], b2[4];
            #pragma unroll
            for (int u = 0; u < 4; ++u) { a[u] = As[ty*4+u][kk]; b2[u] = Vs[kk][tx*4+u]; }
            #pragma unroll
            for (int u = 0; u < 4; ++u)
                #pragma unroll
                for (int w = 0; w < 4; ++w) acc[u][w] += a[u] * b2[w];
        }
        __syncthreads();
    }
    #pragma unroll
    for (int u = 0; u < 4; ++u)
        #pragma unroll
        for (int w = 0; w < 4; ++w)
            ob[(size_t)(i0 + ty*4 + u) * DD + tx*4 + w] = acc[u][w];
}

// ---------------- wavelet filter softmax (per layer): filt[i][d][k] ----------------
__global__ __launch_bounds__(256) void filt_softmax_kernel(const float* __restrict__ w0, const float* __restrict__ w1,
                                                           const float* __restrict__ w2, const float* __restrict__ w3,
                                                           float* __restrict__ filt)
{
    int idx = blockIdx.x * 256 + threadIdx.x;
    if (idx >= 4 * DD) return;
    int d = idx & 511, i = idx >> 9;
    const float* w = (i == 0) ? w0 : (i == 1) ? w1 : (i == 2) ? w2 : w3;
    int K = 4 << i;
    int fb = (i == 0) ? 0 : (i == 1) ? 2048 : (i == 2) ? 6144 : 14336;
    const float* row = w + (size_t)d * K;
    float mx = -1e30f;
    for (int k = 0; k < K; ++k) mx = fmaxf(mx, row[k]);
    float s = 0.f;
    for (int k = 0; k < K; ++k) s += expf(row[k] - mx);
    float inv = 1.f / s;
    float* fo = filt + fb + (size_t)d * K;
    for (int k = 0; k < K; ++k) fo[k] = expf(row[k] - mx) * inv;
}

// ---------------- depthwise causal conv at downsampled positions only ----------------
// dec[((b*Ti)+j)*512 + d] = sum_k h[b, j*stride-(K-1)+k, d] * filt[d*K+k]
__global__ __launch_bounds__(256) void wavelet_dec_kernel(const float* __restrict__ h, const float* __restrict__ filt,
                                                          float* __restrict__ dec, int K, int stride, int Ti)
{
    int idx = blockIdx.x * 256 + threadIdx.x;
    if (idx >= BB * Ti * DD) return;
    int d = idx & 511; int rem = idx >> 9; int j = rem % Ti; int b = rem / Ti;
    int tbase = j * stride - (K - 1);
    float acc = 0.f;
    for (int k = 0; k < K; ++k) {
        int t = tbase + k;
        if (t >= 0) acc += h[((size_t)b * TT + t) * DD + d] * filt[(size_t)d * K + k];
    }
    dec[idx] = acc;
}

// ---------------- linear interp back to T, build comb (B,T,4D) ----------------
__global__ __launch_bounds__(256) void wavelet_interp_kernel(const float* __restrict__ dec, float* __restrict__ comb)
{
    int idx = blockIdx.x * 256 + threadIdx.x;   // over B*T*2048
    int col = idx & 2047; int rem = idx >> 11; int t = rem & 255; int b = rem >> 8;
    if (b >= BB) return;
    int i = col >> 9, d = col & 511;
    int Ti = 256 >> (i + 1);
    const size_t offs[4] = {0, 1048576, 1572864, 1835008};
    float pos = ((float)t + 0.5f) * ((float)Ti / 256.f) - 0.5f;
    pos = fminf(fmaxf(pos, 0.f), (float)(Ti - 1));
    int lo = (int)floorf(pos);
    int hi = min(lo + 1, Ti - 1);
    float w = pos - (float)lo;
    const float* db = dec + offs[i] + (size_t)b * Ti * DD;
    float vlo = db[(size_t)lo * DD + d], vhi = db[(size_t)hi * DD + d];
    comb[idx] = vlo * (1.f - w) + vhi * w;
}

// ---------------- boundary loss: mean(relu(tf.wdiff + bdiff + 0.1)) accumulated ----------------
__global__ __launch_bounds__(256) void bd_loss_kernel(const float* __restrict__ tfb, const float* __restrict__ bdw,
                                                      const float* __restrict__ bdb, float* __restrict__ loss)
{
    int lane = threadIdx.x & 63, wid = threadIdx.x >> 6;
    int row = blockIdx.x * 4 + wid;   // over BT
    float w = bdw[lane * 2] - bdw[lane * 2 + 1];
    float vv = tfb[(size_t)row * PP + lane] * w;
    #pragma unroll
    for (int off = 32; off; off >>= 1) vv += __shfl_xor(vv, off);
    if (lane == 0) {
        float xv = vv + (bdb[0] - bdb[1]) + 0.1f;
        atomicAdd(loss, fmaxf(xv, 0.f) * (1.f / 4096.f));
    }
}

// ---------------- cc_w[l] (O,I,3) -> ccT[k][i][o] ----------------
__global__ __launch_bounds__(256) void cc_transpose_kernel(const float* __restrict__ ccw, float* __restrict__ ccT)
{
    int idx = blockIdx.x * 256 + threadIdx.x;   // 3*512*512
    if (idx >= 3 * DD * DD) return;
    int o = idx & 511; int rem = idx >> 9; int i = rem & 511; int k = rem >> 9;
    ccT[idx] = ccw[((size_t)o * DD + i) * 3 + k];
}

// ---------------- h = layernorm(s + h) * g + b  (s holds geom+wave+td2part+cc) ----------------
__global__ __launch_bounds__(256) void add_ln_kernel(const float* __restrict__ s, float* __restrict__ h,
                                                     const float* __restrict__ g, const float* __restrict__ be)
{
    int lane = threadIdx.x & 63, wid = threadIdx.x >> 6;
    size_t row = (size_t)blockIdx.x * 4 + wid;
    const float* sr = s + row * DD;
    float* hr = h + row * DD;
    float xv[8]; float sum = 0.f;
    #pragma unroll
    for (int u = 0; u < 8; ++u) { int c = lane + u * 64; xv[u] = sr[c] + hr[c]; sum += xv[u]; }
    #pragma unroll
    for (int off = 32; off; off >>= 1) sum += __shfl_xor(sum, off);
    float mu = sum * (1.f / 512.f);
    float sq = 0.f;
    #pragma unroll
    for (int u = 0; u < 8; ++u) { float d = xv[u] - mu; sq += d * d; }
    #pragma unroll
    for (int off = 32; off; off >>= 1) sq += __shfl_xor(sq, off);
    float rstd = 1.f / sqrtf(sq * (1.f / 512.f) + 1e-5f);
    #pragma unroll
    for (int u = 0; u < 8; ++u) { int c = lane + u * 64; hr[c] = (xv[u] - mu) * rstd * g[c] + be[c]; }
}

// ---------------- head helpers ----------------
__global__ void zero_kernel(float* p) { p[0] = 0.f; }

__global__ __launch_bounds__(256) void build_cat_kernel(const float* __restrict__ h, float* __restrict__ catb)
{
    int idx = blockIdx.x * 256 + threadIdx.x;   // 16*1024
    if (idx >= BB * 1024) return;
    int k = idx & 1023, b = idx >> 10;
    float v = (k < 512) ? h[((size_t)b * TT + 255) * DD + k]
                        : h[((size_t)b * TT + 254) * DD + (k - 512)];
    catb[idx] = v;
}

__global__ __launch_bounds__(256) void cur_init_kernel(const float* __restrict__ h, const float* __restrict__ mix,
                                                       float* __restrict__ cur)
{
    int idx = blockIdx.x * 256 + threadIdx.x;   // 16*512
    if (idx >= BB * DD) return;
    int c = idx & 511, b = idx >> 9;
    cur[idx] = h[((size_t)b * TT + 255) * DD + c] + mix[idx];
}

__global__ __launch_bounds__(256) void build_di_kernel(const float* __restrict__ cur, const float* __restrict__ noise_t,
                                                       const float* __restrict__ sched, int t, float* __restrict__ di)
{
    int idx = blockIdx.x * 256 + threadIdx.x;   // 16*1024
    if (idx >= BB * 1024) return;
    int k = idx & 1023, b = idx >> 10;
    float v;
    if (k < 512) {
        v = cur[b * 512 + k] + noise_t[b * 512 + k] * sched[t];
    } else {
        int j = k - 512;
        float tf_ = (float)t;
        const float kfac = -9.210340371976184f / 255.f;   // -ln(10000)/(half-1)
        if (j < 256) v = sinf(tf_ * expf((float)j * kfac));
        else         v = cosf(tf_ * expf((float)(j - 256) * kfac));
    }
    di[idx] = v;
}

__global__ __launch_bounds__(256) void diff_update_kernel(float* __restrict__ cur, const float* __restrict__ npred,
                                                          const float* __restrict__ sched, int t)
{
    int idx = blockIdx.x * 256 + threadIdx.x;   // 16*512
    if (idx >= BB * DD) return;
    cur[idx] -= npred[idx] * sched[t];
}

__global__ void fail_kernel(float* p) { p[0] = 1e30f; }

// =====================================================================================
extern "C" void kernel_launch(void* const* d_in, const int* in_sizes, int n_in,
                              void* d_out, int out_size, void* d_ws, size_t ws_size,
                              hipStream_t stream)
{
    const float* x      = (const float*)d_in[0];
    const float* in_w   = (const float*)d_in[1];
    const float* in_b   = (const float*)d_in[2];
    const float* gq_w   = (const float*)d_in[3];
    const float* gq_b   = (const float*)d_in[4];
    const float* gk_w   = (const float*)d_in[5];
    const float* gk_b   = (const float*)d_in[6];
    const float* gv_w   = (const float*)d_in[7];
    const float* gv_b   = (const float*)d_in[8];
    const float* go_w   = (const float*)d_in[9];
    const float* go_b   = (const float*)d_in[10];
    const float* curv   = (const float*)d_in[11];
    const float* wav0   = (const float*)d_in[12];
    const float* wav1   = (const float*)d_in[13];
    const float* wav2   = (const float*)d_in[14];
    const float* wav3   = (const float*)d_in[15];
    const float* wrec_w = (const float*)d_in[16];
    const float* wrec_b = (const float*)d_in[17];
    const float* te1_w  = (const float*)d_in[18];
    const float* te1_b  = (const float*)d_in[19];
    const float* te2_w  = (const float*)d_in[20];
    const float* te2_b  = (const float*)d_in[21];
    const float* td1_w  = (const float*)d_in[22];
    const float* td1_b  = (const float*)d_in[23];
    const float* td2_w  = (const float*)d_in[24];
    const float* td2_b  = (const float*)d_in[25];
    const float* bd_w   = (const float*)d_in[26];
    const float* bd_b   = (const float*)d_in[27];
    const float* cc_w   = (const float*)d_in[28];
    const float* cc_b   = (const float*)d_in[29];
    const float* ln_g   = (const float*)d_in[30];
    const float* ln_b   = (const float*)d_in[31];
    const float* mm1_w  = (const float*)d_in[32];
    const float* mm1_b  = (const float*)d_in[33];
    const float* mm2_w  = (const float*)d_in[34];
    const float* mm2_b  = (const float*)d_in[35];
    const float* dn1_w  = (const float*)d_in[36];
    const float* dn1_b  = (const float*)d_in[37];
    const float* dn2_w  = (const float*)d_in[38];
    const float* dn2_b  = (const float*)d_in[39];
    const float* dn3_w  = (const float*)d_in[40];
    const float* dn3_b  = (const float*)d_in[41];
    const float* out_w  = (const float*)d_in[42];
    const float* out_b  = (const float*)d_in[43];
    const float* nsched = (const float*)d_in[44];
    const float* noise  = (const float*)d_in[45];
    float* out = (float*)d_out;
    float* ws  = (float*)d_ws;

    // workspace layout (floats)
    const size_t o_h  = 0;                     // BT*DD
    const size_t o_q  = o_h  + (size_t)BT*DD;  // BT*DD (also wavelet dec buffer)
    const size_t o_k  = o_q  + (size_t)BT*DD;
    const size_t o_v  = o_k  + (size_t)BT*DD;
    const size_t o_s  = o_v  + (size_t)BT*DD;
    const size_t o_gm = o_s  + (size_t)BT*DD;  // geomv / td1-out
    const size_t o_t1 = o_gm + (size_t)BT*DD;  // BT*PP
    const size_t o_tf = o_t1 + (size_t)BT*PP;  // BT*PP
    const size_t o_qn = o_tf + (size_t)BT*PP;  // 32768
    const size_t o_kn = o_qn + (size_t)BB*HH*TT;
    const size_t o_at = o_kn + (size_t)BB*HH*TT;   // B*H*T*T (also comb B*T*4D)
    const size_t o_ct = o_at + (size_t)BB*HH*TT*TT; // 3*DD*DD
    const size_t o_fl = o_ct + (size_t)3*DD*DD;     // 30720
    const size_t o_hd = o_fl + 30720;               // head scratch
    const size_t total = o_hd + 82000;
    if (ws_size < total * sizeof(float)) {
        fail_kernel<<<1, 1, 0, stream>>>(out);
        return;
    }
    float* h_   = ws + o_h;
    float* q_   = ws + o_q;
    float* k_   = ws + o_k;
    float* v_   = ws + o_v;
    float* s_   = ws + o_s;
    float* gm_  = ws + o_gm;
    float* t1_  = ws + o_t1;
    float* tf_  = ws + o_tf;
    float* qn_  = ws + o_qn;
    float* kn_  = ws + o_kn;
    float* at_  = ws + o_at;   // attn / comb
    float* ct_  = ws + o_ct;
    float* fl_  = ws + o_fl;
    float* catb = ws + o_hd;            // 16384
    float* tmb  = catb + 16384;         // 8192
    float* mixb = tmb + 8192;           // 8192
    float* curb = mixb + 8192;          // 8192
    float* dib  = curb + 8192;          // 16384
    float* d1b  = dib + 16384;          // 8192
    float* d2b  = d1b + 8192;           // 8192
    float* npb  = d2b + 8192;           // 8192

    auto gemm = [&](const float* A, int lda, const float* W, const float* bias,
                    float* C, int ldc, int M, int N, int K, int shift, int accum, int act) {
        dim3 g((N + 63) / 64, (M + 63) / 64);
        gemm_kernel<<<g, 256, 0, stream>>>(A, lda, W, bias, C, ldc, M, N, K, shift, accum, act);
    };

    zero_kernel<<<1, 1, 0, stream>>>(out + BB * DIN);   // loss accumulator at d_out[6144]

    // h = x @ in_w + in_b
    gemm(x, DIN, in_w, in_b, h_, DD, BT, DD, DIN, 0, 0, ACT_NONE);

    const int Karr[4] = {4, 8, 16, 32};
    const int Sarr[4] = {2, 4, 8, 16};
    const int Tarr[4] = {128, 64, 32, 16};
    const int fbarr[4] = {0, 2048, 6144, 14336};
    const size_t dbarr[4] = {0, 1048576, 1572864, 1835008};

    for (int l = 0; l < LL; ++l) {
        // q, k, v
        gemm(h_, DD, gq_w + (size_t)l*DD*DD, gq_b + (size_t)l*DD, q_, DD, BT, DD, DD, 0, 0, ACT_NONE);
        gemm(h_, DD, gk_w + (size_t)l*DD*DD, gk_b + (size_t)l*DD, k_, DD, BT, DD, DD, 0, 0, ACT_NONE);
        gemm(h_, DD, gv_w + (size_t)l*DD*DD, gv_b + (size_t)l*DD, v_, DD, BT, DD, DD, 0, 0, ACT_NONE);
        // attention
        sqnorm_kernel<<<BB*HH*TT/4, 256, 0, stream>>>(q_, qn_);
        sqnorm_kernel<<<BB*HH*TT/4, 256, 0, stream>>>(k_, kn_);
        qk_kernel<<<dim3(4, 4, BB*HH), 256, 0, stream>>>(q_, k_, at_);
        attn_softmax_kernel<<<BB*HH*TT/4, 256, 0, stream>>>(at_, qn_, kn_, curv + (size_t)l*HH);
        pv_kernel<<<dim3(4, BB*HH), 256, 0, stream>>>(at_, v_, gm_);
        gemm(gm_, DD, go_w + (size_t)l*DD*DD, go_b + (size_t)l*DD, s_, DD, BT, DD, DD, 0, 0, ACT_NONE);
        // wavelet branch (dec buffer aliases q_, comb aliases at_)
        filt_softmax_kernel<<<8, 256, 0, stream>>>(wav0 + (size_t)l*DD*4, wav1 + (size_t)l*DD*8,
                                                   wav2 + (size_t)l*DD*16, wav3 + (size_t)l*DD*32, fl_);
        for (int i = 0; i < 4; ++i) {
            int n = BB * Tarr[i] * DD;
            wavelet_dec_kernel<<<(n + 255) / 256, 256, 0, stream>>>(h_, fl_ + fbarr[i], q_ + dbarr[i],
                                                                    Karr[i], Sarr[i], Tarr[i]);
        }
        wavelet_interp_kernel<<<(BT * 2048) / 256, 256, 0, stream>>>(q_, at_);
        gemm(at_, 2048, wrec_w + (size_t)l*2048*DD, wrec_b + (size_t)l*DD, s_, DD, BT, DD, 2048, 0, 1, ACT_NONE);
        // topo branch
        gemm(h_, DD, te1_w + (size_t)l*DD*PP, te1_b + (size_t)l*PP, t1_, PP, BT, PP, DD, 0, 0, ACT_RELU);
        gemm(t1_, PP, te2_w + (size_t)l*PP*PP, te2_b + (size_t)l*PP, tf_, PP, BT, PP, PP, 0, 0, ACT_NONE);
        bd_loss_kernel<<<BT/4, 256, 0, stream>>>(tf_, bd_w + (size_t)l*PP*2, bd_b + (size_t)l*2, out + BB*DIN);
        gemm(tf_, PP, td1_w + (size_t)l*PP*DD, td1_b + (size_t)l*DD, gm_, DD, BT, DD, PP, 0, 0, ACT_RELU);
        gemm(gm_, DD, td2_w + (size_t)l*DD*DD, td2_b + (size_t)l*DD, s_, DD, BT, DD, DD, 0, 1, ACT_NONE);
        // causal dilated conv via 3 shifted GEMMs
        cc_transpose_kernel<<<(3*DD*DD)/256, 256, 0, stream>>>(cc_w + (size_t)l*DD*DD*3, ct_);
        int dil = 1 << l;
        for (int kk = 0; kk < 3; ++kk) {
            int shift = (2 - kk) * dil;
            gemm(h_, DD, ct_ + (size_t)kk*DD*DD, (kk == 2) ? (cc_b + (size_t)l*DD) : nullptr,
                 s_, DD, BT, DD, DD, shift, 1, ACT_NONE);
        }
        // h = LN(s + h) (the "+h" is topo's residual)
        add_ln_kernel<<<BT/4, 256, 0, stream>>>(s_, h_, ln_g, ln_b);
    }

    // ---- head ----
    build_cat_kernel<<<64, 256, 0, stream>>>(h_, catb);
    gemm(catb, 1024, mm1_w, mm1_b, tmb, DD, BB, DD, 1024, 0, 0, ACT_TANH);
    gemm(tmb, DD, mm2_w, mm2_b, mixb, DD, BB, DD, DD, 0, 0, ACT_NONE);
    cur_init_kernel<<<32, 256, 0, stream>>>(h_, mixb, curb);
    for (int t = 0; t < SS; ++t) {
        build_di_kernel<<<64, 256, 0, stream>>>(curb, noise + (size_t)t*BB*DD, nsched, t, dib);
        gemm(dib, 1024, dn1_w, dn1_b, d1b, DD, BB, DD, 1024, 0, 0, ACT_SILU);
        gemm(d1b, DD, dn2_w, dn2_b, d2b, DD, BB, DD, DD, 0, 0, ACT_SILU);
        gemm(d2b, DD, dn3_w, dn3_b, npb, DD, BB, DD, DD, 0, 0, ACT_NONE);
        diff_update_kernel<<<32, 256, 0, stream>>>(curb, npb, nsched, t);
    }
    gemm(curb, DD, out_w, out_b, out, DIN, BB, DIN, DD, 0, 0, ACT_NONE);
}

// Round 2
// 3702.445 us; speedup vs baseline: 2.4896x; 2.4896x over previous
//
#include <hip/hip_runtime.h>
#include <hip/hip_bf16.h>
#include <math.h>

#define BB 16
#define TT 256
#define DIN 384
#define DD 512
#define LL 6
#define HH 8
#define PP 64
#define SS 10
#define BT (BB*TT)   // 4096

enum { ACT_NONE=0, ACT_RELU=1, ACT_TANH=2, ACT_SILU=3 };

typedef __attribute__((ext_vector_type(8))) short bf16x8;
typedef __attribute__((ext_vector_type(4))) float f32x4;
typedef __hip_bfloat16 bh16;

typedef const __attribute__((address_space(1))) void gvoid_t;
typedef __attribute__((address_space(3))) void lvoid_t;
__device__ __forceinline__ void gload16(const void* g, void* l) {
    __builtin_amdgcn_global_load_lds((gvoid_t*)g, (lvoid_t*)l, 16, 0, 0);
}

// =====================================================================================
// Generic bf16 MFMA GEMM: C = act(A @ Bt^T + bias)  (Bt stored [N][K])
// BM=128, BN=64, BK=64; 4 waves 2x2, wave tile 64x32 (4x2 frags of 16x16).
// Optional batch dim z: z1=z>>zshift, z0=z&zmask; element-offsets per z1/z0.
// shift: A-row for output row r is (r-shift), valid iff (r%256)>=shift (else zero-page).
// Outputs: Cf fp32 (accum optional) and/or Cb bf16, both ldc.
__global__ __launch_bounds__(256) void mgemm_kernel(
    const bh16* __restrict__ A, int lda,
    const bh16* __restrict__ Bt, int ldb,
    const float* __restrict__ bias,
    float* __restrict__ Cf, bh16* __restrict__ Cb, int ldc,
    int N, int K, int shift, int accum, int act,
    int zmask, int zshift,
    long aS1, long aS0, long bS1, long bS0, long cS1, long cS0,
    const bh16* __restrict__ zp)
{
    __shared__ bf16x8 As[128*8];   // 16KB: [row][8 chunks], chunk XOR-swizzled by row&7
    __shared__ bf16x8 Bs[64*8];    // 8KB

    int z = blockIdx.z;
    long z1 = (long)(z >> zshift), z0 = (long)(z & zmask);
    A  += z1*aS1 + z0*aS0;
    Bt += z1*bS1 + z0*bS0;
    long coff = z1*cS1 + z0*cS0;

    const int tid  = threadIdx.x;
    const int lane = tid & 63, w = tid >> 6;
    const int wm = w >> 1, wn = w & 1;
    const int row0 = blockIdx.y * 128, col0 = blockIdx.x * 64;

    f32x4 acc[4][2];
    #pragma unroll
    for (int i = 0; i < 4; ++i)
        #pragma unroll
        for (int j = 0; j < 2; ++j) acc[i][j] = (f32x4){0.f,0.f,0.f,0.f};

    const int nkt = K >> 6;
    for (int kt = 0; kt < nkt; ++kt) {
        int k0 = kt << 6;
        // stage A: 1024 16B-chunks, 4 instr/wave
        #pragma unroll
        for (int j = 0; j < 4; ++j) {
            int c = ((w*4 + j) << 6) + lane;
            int row = c >> 3, chk = c & 7;
            int schk = chk ^ (row & 7);
            int grow = row0 + row;
            const bh16* src = ((grow & 255) >= shift)
                ? (A + (size_t)(grow - shift)*lda + k0 + schk*8) : zp;
            gload16(src, &As[(w*4 + j) * 64]);
        }
        // stage B: 512 chunks, 2 instr/wave
        #pragma unroll
        for (int j = 0; j < 2; ++j) {
            int c = ((w*2 + j) << 6) + lane;
            int row = c >> 3, chk = c & 7;
            int schk = chk ^ (row & 7);
            int gcol = col0 + row;
            const bh16* src = (gcol < N)
                ? (Bt + (size_t)gcol*ldb + k0 + schk*8) : zp;
            gload16(src, &Bs[(w*2 + j) * 64]);
        }
        asm volatile("s_waitcnt vmcnt(0)" ::: "memory");
        __syncthreads();

        bf16x8 a[4][2], b[2][2];
        #pragma unroll
        for (int fm = 0; fm < 4; ++fm) {
            int row = wm*64 + fm*16 + (lane & 15);
            #pragma unroll
            for (int ks = 0; ks < 2; ++ks)
                a[fm][ks] = As[row*8 + ((ks*4 + (lane>>4)) ^ (row & 7))];
        }
        #pragma unroll
        for (int fn = 0; fn < 2; ++fn) {
            int col = wn*32 + fn*16 + (lane & 15);
            #pragma unroll
            for (int ks = 0; ks < 2; ++ks)
                b[fn][ks] = Bs[col*8 + ((ks*4 + (lane>>4)) ^ (col & 7))];
        }
        #pragma unroll
        for (int ks = 0; ks < 2; ++ks)
            #pragma unroll
            for (int fm = 0; fm < 4; ++fm)
                #pragma unroll
                for (int fn = 0; fn < 2; ++fn)
                    acc[fm][fn] = __builtin_amdgcn_mfma_f32_16x16x32_bf16(
                        a[fm][ks], b[fn][ks], acc[fm][fn], 0, 0, 0);
        __syncthreads();
    }

    // epilogue: D[row][col], col=lane&15, row=(lane>>4)*4+r
    #pragma unroll
    for (int fm = 0; fm < 4; ++fm) {
        #pragma unroll
        for (int fn = 0; fn < 2; ++fn) {
            int gc = col0 + wn*32 + fn*16 + (lane & 15);
            float bs = bias ? bias[gc] : 0.f;
            #pragma unroll
            for (int r = 0; r < 4; ++r) {
                int gr = row0 + wm*64 + fm*16 + (lane>>4)*4 + r;
                float v = acc[fm][fn][r] + bs;
                if (act == ACT_RELU) v = fmaxf(v, 0.f);
                size_t o = (size_t)gr*ldc + gc + coff;
                if (Cf) { if (accum) Cf[o] += v; else Cf[o] = v; }
                if (Cb) Cb[o] = __float2bfloat16(v);
            }
        }
    }
}

// ---------------- per-head squared norms for q and k (bf16 in) ----------------
__global__ __launch_bounds__(256) void sqnorm2_kernel(const bh16* __restrict__ qb, const bh16* __restrict__ kb,
                                                      float* __restrict__ qn, float* __restrict__ kn)
{
    int lane = threadIdx.x & 63, wid = threadIdx.x >> 6;
    int row = blockIdx.x * 4 + wid;            // over B*H*T
    const bh16* src = blockIdx.y ? kb : qb;
    float* dst = blockIdx.y ? kn : qn;
    int t = row & 255; int bh = row >> 8; int b = bh >> 3, hh = bh & 7;
    float v = __bfloat162float(src[((size_t)b * TT + t) * DD + hh * 64 + lane]);
    float s = v * v;
    #pragma unroll
    for (int off = 32; off; off >>= 1) s += __shfl_xor(s, off);
    if (lane == 0) dst[row] = s;
}

// ---------------- hyperbolic distance + softmax: fp32 logits in, bf16 probs out ----------------
__global__ __launch_bounds__(256) void attn_softmax_kernel(const float* __restrict__ at, bh16* __restrict__ pb,
                                                           const float* __restrict__ qn,
                                                           const float* __restrict__ kn,
                                                           const float* __restrict__ curv)
{
    int lane = threadIdx.x & 63, wid = threadIdx.x >> 6;
    int row = blockIdx.x * 4 + wid;            // over B*H*T
    int i = row & 255; int bh = row >> 8; int hh = bh & 7;
    float c = fabsf(curv[hh]) + 1e-8f;
    float inv_sqrt_c = 1.f / sqrtf(c);
    float qni = qn[row];
    const float* srow = at + (size_t)bh * TT * TT + (size_t)i * TT;
    bh16* prow = pb + (size_t)bh * TT * TT + (size_t)i * TT;
    const float* knr = kn + (size_t)bh * TT;
    float logit[4];
    float mx = -1e30f;
    #pragma unroll
    for (int u = 0; u < 4; ++u) {
        int j = lane + u * 64;
        float s = srow[j];
        float knj = knr[j];
        float d2 = fmaxf(qni + knj - 2.f * s, 0.f);
        float denom = fmaxf((1.f - c * qni) * (1.f - c * knj), 1e-5f);
        float arg = fmaxf(1.f + (2.f * c * d2) / denom, 1.00001f);
        float dist = logf(arg + sqrtf((arg - 1.f) * (arg + 1.f))) * inv_sqrt_c;
        logit[u] = -dist;
        mx = fmaxf(mx, logit[u]);
    }
    #pragma unroll
    for (int off = 32; off; off >>= 1) mx = fmaxf(mx, __shfl_xor(mx, off));
    float e[4]; float sum = 0.f;
    #pragma unroll
    for (int u = 0; u < 4; ++u) { e[u] = expf(logit[u] - mx); sum += e[u]; }
    #pragma unroll
    for (int off = 32; off; off >>= 1) sum += __shfl_xor(sum, off);
    float inv = 1.f / sum;
    #pragma unroll
    for (int u = 0; u < 4; ++u) prow[lane + u * 64] = __float2bfloat16(e[u] * inv);
}

// ---------------- V transpose per (b,h): vb[b][t][h*64+d] -> vt[bh][d][t] ----------------
__global__ __launch_bounds__(256) void vtrans_kernel(const bh16* __restrict__ vb, bh16* __restrict__ vt)
{
    int bh = blockIdx.y, b = bh >> 3, hh = bh & 7;
    int t0 = blockIdx.x * 64;
    __shared__ bh16 tile[64][65];
    for (int e = threadIdx.x; e < 4096; e += 256) {
        int r = e >> 6, c = e & 63;
        tile[r][c] = vb[((size_t)(b*256 + t0 + r))*512 + hh*64 + c];
    }
    __syncthreads();
    for (int e = threadIdx.x; e < 4096; e += 256) {
        int d = e >> 6, t2 = e & 63;
        vt[((size_t)bh*64 + d)*256 + t0 + t2] = tile[t2][d];
    }
}

// ---------------- wavelet filter softmax ----------------
__global__ __launch_bounds__(256) void filt_softmax_kernel(const float* __restrict__ w0, const float* __restrict__ w1,
                                                           const float* __restrict__ w2, const float* __restrict__ w3,
                                                           float* __restrict__ filt)
{
    int idx = blockIdx.x * 256 + threadIdx.x;
    if (idx >= 4 * DD) return;
    int d = idx & 511, i = idx >> 9;
    const float* w = (i == 0) ? w0 : (i == 1) ? w1 : (i == 2) ? w2 : w3;
    int K = 4 << i;
    int fb = (i == 0) ? 0 : (i == 1) ? 2048 : (i == 2) ? 6144 : 14336;
    const float* row = w + (size_t)d * K;
    float mx = -1e30f;
    for (int k = 0; k < K; ++k) mx = fmaxf(mx, row[k]);
    float s = 0.f;
    for (int k = 0; k < K; ++k) s += expf(row[k] - mx);
    float inv = 1.f / s;
    float* fo = filt + fb + (size_t)d * K;
    for (int k = 0; k < K; ++k) fo[k] = expf(row[k] - mx) * inv;
}

// ---------------- all 4 wavelet decompositions fused ----------------
__global__ __launch_bounds__(256) void wdec_kernel(const float* __restrict__ h, const float* __restrict__ filt,
                                                   float* __restrict__ dec)
{
    int idx = blockIdx.x * 256 + threadIdx.x;   // < 1966080
    int i, base;
    if (idx < 1048576)      { i = 0; base = 0; }
    else if (idx < 1572864) { i = 1; base = 1048576; }
    else if (idx < 1835008) { i = 2; base = 1572864; }
    else                    { i = 3; base = 1835008; }
    int loc = idx - base;
    int K = 4 << i, stride = 2 << i, lgTi = 7 - i, Ti = 128 >> i;
    const int fbarr[4] = {0, 2048, 6144, 14336};
    int d = loc & 511; int rem = loc >> 9; int j = rem & (Ti - 1); int b = rem >> lgTi;
    const float* frow = filt + fbarr[i] + (size_t)d * K;
    int tbase = j * stride - (K - 1);
    float acc = 0.f;
    for (int k = 0; k < K; ++k) {
        int t = tbase + k;
        if (t >= 0) acc += h[((size_t)b * TT + t) * DD + d] * frow[k];
    }
    dec[idx] = acc;
}

// ---------------- linear interp back to T: comb (B,T,4D) bf16 ----------------
__global__ __launch_bounds__(256) void winterp_kernel(const float* __restrict__ dec, bh16* __restrict__ comb)
{
    int idx = blockIdx.x * 256 + threadIdx.x;   // over B*T*2048
    int col = idx & 2047; int rem = idx >> 11; int t = rem & 255; int b = rem >> 8;
    if (b >= BB) return;
    int i = col >> 9, d = col & 511;
    int Ti = 256 >> (i + 1);
    const size_t offs[4] = {0, 1048576, 1572864, 1835008};
    float pos = ((float)t + 0.5f) * ((float)Ti / 256.f) - 0.5f;
    pos = fminf(fmaxf(pos, 0.f), (float)(Ti - 1));
    int lo = (int)floorf(pos);
    int hi = min(lo + 1, Ti - 1);
    float w = pos - (float)lo;
    const float* db = dec + offs[i] + (size_t)b * Ti * DD;
    float vlo = db[(size_t)lo * DD + d], vhi = db[(size_t)hi * DD + d];
    comb[idx] = __float2bfloat16(vlo * (1.f - w) + vhi * w);
}

// ---------------- boundary loss ----------------
__global__ __launch_bounds__(256) void bd_loss_kernel(const float* __restrict__ tfb, const float* __restrict__ bdw,
                                                      const float* __restrict__ bdb, float* __restrict__ loss)
{
    int lane = threadIdx.x & 63, wid = threadIdx.x >> 6;
    int row = blockIdx.x * 4 + wid;   // over BT
    float w = bdw[lane * 2] - bdw[lane * 2 + 1];
    float vv = tfb[(size_t)row * PP + lane] * w;
    #pragma unroll
    for (int off = 32; off; off >>= 1) vv += __shfl_xor(vv, off);
    if (lane == 0) {
        float xv = vv + (bdb[0] - bdb[1]) + 0.1f;
        atomicAdd(loss, fmaxf(xv, 0.f) * (1.f / 4096.f));
    }
}

// ---------------- h = layernorm(s + h)*g + b, dual fp32+bf16 out ----------------
__global__ __launch_bounds__(256) void add_ln_kernel(const float* __restrict__ s, float* __restrict__ h,
                                                     bh16* __restrict__ hb,
                                                     const float* __restrict__ g, const float* __restrict__ be)
{
    int lane = threadIdx.x & 63, wid = threadIdx.x >> 6;
    size_t row = (size_t)blockIdx.x * 4 + wid;
    const float* sr = s + row * DD;
    float* hr = h + row * DD;
    bh16* hbr = hb + row * DD;
    float xv[8]; float sum = 0.f;
    #pragma unroll
    for (int u = 0; u < 8; ++u) { int c = lane + u * 64; xv[u] = sr[c] + hr[c]; sum += xv[u]; }
    #pragma unroll
    for (int off = 32; off; off >>= 1) sum += __shfl_xor(sum, off);
    float mu = sum * (1.f / 512.f);
    float sq = 0.f;
    #pragma unroll
    for (int u = 0; u < 8; ++u) { float d = xv[u] - mu; sq += d * d; }
    #pragma unroll
    for (int off = 32; off; off >>= 1) sq += __shfl_xor(sq, off);
    float rstd = 1.f / sqrtf(sq * (1.f / 512.f) + 1e-5f);
    #pragma unroll
    for (int u = 0; u < 8; ++u) {
        int c = lane + u * 64;
        float v = (xv[u] - mu) * rstd * g[c] + be[c];
        hr[c] = v;
        hbr[c] = __float2bfloat16(v);
    }
}

// ---------------- weight transpose-convert: [L][K][N] f32 -> [L][N][K] bf16 ----------------
__global__ __launch_bounds__(256) void wtrans_kernel(const float* __restrict__ W, bh16* __restrict__ Wt,
                                                     int K, int N)
{
    int l = blockIdx.z;
    const float* Wl = W + (size_t)l * K * N;
    bh16* Wo = Wt + (size_t)l * N * K;
    __shared__ float tile[32][33];
    int n0 = blockIdx.x * 32, k0 = blockIdx.y * 32;
    int lx = threadIdx.x & 31, ly = threadIdx.x >> 5;
    #pragma unroll
    for (int j = 0; j < 4; ++j) {
        int kk = ly + j * 8;
        tile[kk][lx] = Wl[(size_t)(k0 + kk) * N + n0 + lx];
    }
    __syncthreads();
    #pragma unroll
    for (int j = 0; j < 4; ++j) {
        int nr = ly + j * 8;
        Wo[(size_t)(n0 + nr) * K + k0 + lx] = __float2bfloat16(tile[lx][nr]);
    }
}

// ---------------- cc_w [L][O][I][3] f32 -> ccT [L][3][O][I] bf16 ----------------
__global__ __launch_bounds__(256) void ccconv_kernel(const float* __restrict__ ccw, bh16* __restrict__ ccT)
{
    size_t idx = (size_t)blockIdx.x * 256 + threadIdx.x;   // 6*3*512*512
    int i = idx & 511; size_t rem = idx >> 9;
    int o = rem & 511; rem >>= 9;
    int k = (int)(rem % 3); int l = (int)(rem / 3);
    ccT[idx] = __float2bfloat16(ccw[(((size_t)l*512 + o)*512 + i)*3 + k]);
}

// ---------------- x f32 -> bf16 ----------------
__global__ __launch_bounds__(256) void convx_kernel(const float* __restrict__ x, bh16* __restrict__ xb)
{
    size_t idx = (size_t)blockIdx.x * 256 + threadIdx.x;
    xb[idx] = __float2bfloat16(x[idx]);
}

// ---------------- small M=16 fp32 GEMM for the head ----------------
// amode: 0=direct A[16][K], 1=build di from cur/noise/t.
// omode: 0=store outp[16][N] with act, 1=cur[r*512+c] -= v*sched[t]
__global__ __launch_bounds__(256) void sg16_kernel(
    const float* __restrict__ A, const float* __restrict__ W, const float* __restrict__ bias,
    float* __restrict__ outp, int K, int N, int act,
    float* __restrict__ cur, const float* __restrict__ noise_t, const float* __restrict__ sched,
    int t, int amode, int omode)
{
    __shared__ float As[16][128];
    __shared__ float Ws[128][65];
    int c0 = blockIdx.x * 64;
    int c = threadIdx.x & 63, rg = threadIdx.x >> 6;
    float acc[4] = {0.f, 0.f, 0.f, 0.f};
    for (int k0 = 0; k0 < K; k0 += 128) {
        for (int i = threadIdx.x; i < 16 * 128; i += 256) {
            int r = i >> 7, kk = i & 127; int k = k0 + kk;
            float v;
            if (amode == 0) v = A[(size_t)r * K + k];
            else {
                if (k < 512) v = cur[r * 512 + k] + noise_t[r * 512 + k] * sched[t];
                else {
                    int j = k - 512;
                    const float kfac = -9.210340371976184f / 255.f;
                    v = (j < 256) ? sinf((float)t * expf((float)j * kfac))
                                  : cosf((float)t * expf((float)(j - 256) * kfac));
                }
            }
            As[r][kk] = v;
        }
        for (int i = threadIdx.x; i < 128 * 64; i += 256) {
            int kk = i >> 6, cc = i & 63;
            Ws[kk][cc] = W[(size_t)(k0 + kk) * N + c0 + cc];
        }
        __syncthreads();
        #pragma unroll 4
        for (int kk = 0; kk < 128; ++kk) {
            float wv = Ws[kk][c];
            #pragma unroll
            for (int u = 0; u < 4; ++u) acc[u] += As[rg * 4 + u][kk] * wv;
        }
        __syncthreads();
    }
    #pragma unroll
    for (int u = 0; u < 4; ++u) {
        int r = rg * 4 + u; int cc = c0 + c;
        float v = acc[u] + (bias ? bias[cc] : 0.f);
        if (act == ACT_TANH)      v = tanhf(v);
        else if (act == ACT_SILU) v = v / (1.f + expf(-v));
        if (omode == 0) outp[(size_t)r * N + cc] = v;
        else cur[r * 512 + cc] -= v * sched[t];
    }
}

// ---------------- head helpers ----------------
__global__ void init_kernel(bh16* zp, float* loss)
{
    int t = threadIdx.x;
    if (t < 64) zp[t] = __float2bfloat16(0.f);
    if (t == 64) *loss = 0.f;
}

__global__ __launch_bounds__(256) void build_cat_kernel(const float* __restrict__ h, float* __restrict__ catb)
{
    int idx = blockIdx.x * 256 + threadIdx.x;   // 16*1024
    if (idx >= BB * 1024) return;
    int k = idx & 1023, b = idx >> 10;
    float v = (k < 512) ? h[((size_t)b * TT + 255) * DD + k]
                        : h[((size_t)b * TT + 254) * DD + (k - 512)];
    catb[idx] = v;
}

__global__ __launch_bounds__(256) void cur_init_kernel(const float* __restrict__ h, const float* __restrict__ mix,
                                                       float* __restrict__ cur)
{
    int idx = blockIdx.x * 256 + threadIdx.x;   // 16*512
    if (idx >= BB * DD) return;
    int c = idx & 511, b = idx >> 9;
    cur[idx] = h[((size_t)b * TT + 255) * DD + c] + mix[idx];
}

__global__ void fail_kernel(float* p) { p[0] = 1e30f; }

// =====================================================================================
extern "C" void kernel_launch(void* const* d_in, const int* in_sizes, int n_in,
                              void* d_out, int out_size, void* d_ws, size_t ws_size,
                              hipStream_t stream)
{
    const float* x      = (const float*)d_in[0];
    const float* in_w   = (const float*)d_in[1];
    const float* in_b   = (const float*)d_in[2];
    const float* gq_w   = (const float*)d_in[3];
    const float* gq_b   = (const float*)d_in[4];
    const float* gk_w   = (const float*)d_in[5];
    const float* gk_b   = (const float*)d_in[6];
    const float* gv_w   = (const float*)d_in[7];
    const float* gv_b   = (const float*)d_in[8];
    const float* go_w   = (const float*)d_in[9];
    const float* go_b   = (const float*)d_in[10];
    const float* curv   = (const float*)d_in[11];
    const float* wav0   = (const float*)d_in[12];
    const float* wav1   = (const float*)d_in[13];
    const float* wav2   = (const float*)d_in[14];
    const float* wav3   = (const float*)d_in[15];
    const float* wrec_w = (const float*)d_in[16];
    const float* wrec_b = (const float*)d_in[17];
    const float* te1_w  = (const float*)d_in[18];
    const float* te1_b  = (const float*)d_in[19];
    const float* te2_w  = (const float*)d_in[20];
    const float* te2_b  = (const float*)d_in[21];
    const float* td1_w  = (const float*)d_in[22];
    const float* td1_b  = (const float*)d_in[23];
    const float* td2_w  = (const float*)d_in[24];
    const float* td2_b  = (const float*)d_in[25];
    const float* bd_w   = (const float*)d_in[26];
    const float* bd_b   = (const float*)d_in[27];
    const float* cc_w   = (const float*)d_in[28];
    const float* cc_b   = (const float*)d_in[29];
    const float* ln_g   = (const float*)d_in[30];
    const float* ln_b   = (const float*)d_in[31];
    const float* mm1_w  = (const float*)d_in[32];
    const float* mm1_b  = (const float*)d_in[33];
    const float* mm2_w  = (const float*)d_in[34];
    const float* mm2_b  = (const float*)d_in[35];
    const float* dn1_w  = (const float*)d_in[36];
    const float* dn1_b  = (const float*)d_in[37];
    const float* dn2_w  = (const float*)d_in[38];
    const float* dn2_b  = (const float*)d_in[39];
    const float* dn3_w  = (const float*)d_in[40];
    const float* dn3_b  = (const float*)d_in[41];
    const float* out_w  = (const float*)d_in[42];
    const float* out_b  = (const float*)d_in[43];
    const float* nsched = (const float*)d_in[44];
    const float* noise  = (const float*)d_in[45];
    float* out = (float*)d_out;
    float* ws  = (float*)d_ws;

    // ---- fp32 workspace layout (float offsets) ----
    const size_t o_h   = 0;          // 2097152
    const size_t o_dec = 2097152;    // 2097152
    const size_t o_s   = 4194304;    // 2097152
    const size_t o_tf  = 6291456;    // 262144
    const size_t o_qn  = 6553600;    // 32768
    const size_t o_kn  = 6586368;    // 32768
    const size_t o_at  = 6619136;    // 8388608
    const size_t o_fl  = 15007744;   // 30720
    const size_t o_cat = 15038464;   // 16384
    const size_t o_tmb = 15054848;   // 8192
    const size_t o_mix = 15063040;   // 8192
    const size_t o_cur = 15071232;   // 8192
    const size_t o_d1  = 15079424;   // 8192
    const size_t o_d2  = 15087616;   // 8192
    const size_t FP32_TOTAL = 15095808;
    // ---- bf16 region (short offsets from bp) ----
    const size_t b_xb   = 0;          // 1572864
    const size_t b_hb   = 1572864;    // 2097152
    const size_t b_qb   = 3670016;
    const size_t b_kb   = 5767168;
    const size_t b_vb   = 7864320;
    const size_t b_vt   = 9961472;
    const size_t b_pb   = 12058624;   // 8388608
    const size_t b_gmb  = 20447232;
    const size_t b_tdb  = 22544384;
    const size_t b_t1b  = 24641536;   // 262144
    const size_t b_tfb  = 24903680;   // 262144
    const size_t b_zp   = 25165824;   // 512
    const size_t b_inwT = 25166336;   // 196608
    const size_t b_gqT  = 25362944;   // 1572864
    const size_t b_gkT  = 26935808;
    const size_t b_gvT  = 28508672;
    const size_t b_goT  = 30081536;
    const size_t b_wrT  = 31654400;   // 6291456
    const size_t b_td1T = 37945856;   // 196608
    const size_t b_td2T = 38142464;   // 1572864
    const size_t b_te1T = 39715328;   // 196608
    const size_t b_te2T = 39911936;   // 24576
    const size_t b_ccT  = 39936512;   // 4718592
    const size_t BF16_TOTAL = 44655104;
    const size_t TOTAL_BYTES = FP32_TOTAL * 4 + BF16_TOTAL * 2;
    if (ws_size < TOTAL_BYTES) { fail_kernel<<<1, 1, 0, stream>>>(out); return; }

    float* h_   = ws + o_h;
    float* dec_ = ws + o_dec;
    float* s_   = ws + o_s;
    float* tf_  = ws + o_tf;
    float* qn_  = ws + o_qn;
    float* kn_  = ws + o_kn;
    float* at_  = ws + o_at;
    float* fl_  = ws + o_fl;
    float* catb = ws + o_cat;
    float* tmb  = ws + o_tmb;
    float* mixb = ws + o_mix;
    float* curb = ws + o_cur;
    float* d1b  = ws + o_d1;
    float* d2b  = ws + o_d2;
    bh16* bp   = (bh16*)(ws + FP32_TOTAL);
    bh16* xb   = bp + b_xb;
    bh16* hb   = bp + b_hb;
    bh16* qb   = bp + b_qb;
    bh16* kb   = bp + b_kb;
    bh16* vb   = bp + b_vb;
    bh16* vt   = bp + b_vt;
    bh16* pb   = bp + b_pb;
    bh16* gmb  = bp + b_gmb;
    bh16* tdb  = bp + b_tdb;
    bh16* t1b  = bp + b_t1b;
    bh16* tfb  = bp + b_tfb;
    bh16* zp   = bp + b_zp;
    bh16* inwT = bp + b_inwT;
    bh16* gqT  = bp + b_gqT;
    bh16* gkT  = bp + b_gkT;
    bh16* gvT  = bp + b_gvT;
    bh16* goT  = bp + b_goT;
    bh16* wrT  = bp + b_wrT;
    bh16* td1T = bp + b_td1T;
    bh16* td2T = bp + b_td2T;
    bh16* te1T = bp + b_te1T;
    bh16* te2T = bp + b_te2T;
    bh16* ccT  = bp + b_ccT;
    bh16* combb = (bh16*)at_;   // aliases at_ after softmax consumed it

    auto mg = [&](const bh16* A, int lda, const bh16* Bt, int ldb,
                  const float* bias, float* Cf, bh16* Cb, int ldc,
                  int M, int N, int K, int shift, int accum, int act,
                  int nb, int zmask, int zshift,
                  long aS1, long aS0, long bS1, long bS0, long cS1, long cS0) {
        dim3 g(N / 64, M / 128, nb);
        mgemm_kernel<<<g, 256, 0, stream>>>(A, lda, Bt, ldb, bias, Cf, Cb, ldc, N, K,
                                            shift, accum, act, zmask, zshift,
                                            aS1, aS0, bS1, bS0, cS1, cS0, zp);
    };
    auto mgp = [&](const bh16* A, int lda, const bh16* Bt, int ldb,
                   const float* bias, float* Cf, bh16* Cb, int ldc,
                   int M, int N, int K, int shift, int accum, int act) {
        mg(A, lda, Bt, ldb, bias, Cf, Cb, ldc, M, N, K, shift, accum, act, 1, 0, 0, 0, 0, 0, 0, 0, 0);
    };

    // ---- setup: zero page/loss, converts ----
    init_kernel<<<1, 128, 0, stream>>>(zp, out + BB * DIN);
    convx_kernel<<<BT * DIN / 256, 256, 0, stream>>>(x, xb);
    wtrans_kernel<<<dim3(DD/32, DIN/32, 1), 256, 0, stream>>>(in_w, inwT, DIN, DD);
    wtrans_kernel<<<dim3(16, 16, 6), 256, 0, stream>>>(gq_w, gqT, DD, DD);
    wtrans_kernel<<<dim3(16, 16, 6), 256, 0, stream>>>(gk_w, gkT, DD, DD);
    wtrans_kernel<<<dim3(16, 16, 6), 256, 0, stream>>>(gv_w, gvT, DD, DD);
    wtrans_kernel<<<dim3(16, 16, 6), 256, 0, stream>>>(go_w, goT, DD, DD);
    wtrans_kernel<<<dim3(16, 64, 6), 256, 0, stream>>>(wrec_w, wrT, 2048, DD);
    wtrans_kernel<<<dim3(16, 2, 6), 256, 0, stream>>>(td1_w, td1T, PP, DD);
    wtrans_kernel<<<dim3(16, 16, 6), 256, 0, stream>>>(td2_w, td2T, DD, DD);
    wtrans_kernel<<<dim3(2, 16, 6), 256, 0, stream>>>(te1_w, te1T, DD, PP);
    wtrans_kernel<<<dim3(2, 2, 6), 256, 0, stream>>>(te2_w, te2T, PP, PP);
    ccconv_kernel<<<18432, 256, 0, stream>>>(cc_w, ccT);

    // h = x @ in_w + in_b  (fp32 + bf16)
    mgp(xb, DIN, inwT, DIN, in_b, h_, hb, DD, BT, DD, DIN, 0, 0, ACT_NONE);

    for (int l = 0; l < LL; ++l) {
        // q, k, v (bf16 only)
        mgp(hb, DD, gqT + (size_t)l*262144, DD, gq_b + (size_t)l*DD, nullptr, qb, DD, BT, DD, DD, 0, 0, ACT_NONE);
        mgp(hb, DD, gkT + (size_t)l*262144, DD, gk_b + (size_t)l*DD, nullptr, kb, DD, BT, DD, DD, 0, 0, ACT_NONE);
        mgp(hb, DD, gvT + (size_t)l*262144, DD, gv_b + (size_t)l*DD, nullptr, vb, DD, BT, DD, DD, 0, 0, ACT_NONE);
        // attention
        sqnorm2_kernel<<<dim3(8192, 2), 256, 0, stream>>>(qb, kb, qn_, kn_);
        mg(qb, DD, kb, DD, nullptr, at_, nullptr, TT, TT, TT, 64, 0, 0, ACT_NONE,
           128, 7, 3, 131072, 64, 131072, 64, 524288, 65536);
        attn_softmax_kernel<<<8192, 256, 0, stream>>>(at_, pb, qn_, kn_, curv + (size_t)l*HH);
        vtrans_kernel<<<dim3(4, 128), 256, 0, stream>>>(vb, vt);
        mg(pb, TT, vt, TT, nullptr, nullptr, gmb, DD, TT, 64, TT, 0, 0, ACT_NONE,
           128, 7, 3, 524288, 65536, 131072, 16384, 131072, 64);
        mgp(gmb, DD, goT + (size_t)l*262144, DD, go_b + (size_t)l*DD, s_, nullptr, DD, BT, DD, DD, 0, 0, ACT_NONE);
        // wavelet branch
        filt_softmax_kernel<<<8, 256, 0, stream>>>(wav0 + (size_t)l*DD*4, wav1 + (size_t)l*DD*8,
                                                   wav2 + (size_t)l*DD*16, wav3 + (size_t)l*DD*32, fl_);
        wdec_kernel<<<7680, 256, 0, stream>>>(h_, fl_, dec_);
        winterp_kernel<<<(BT * 2048) / 256, 256, 0, stream>>>(dec_, combb);
        mgp(combb, 2048, wrT + (size_t)l*1048576, 2048, wrec_b + (size_t)l*DD, s_, nullptr, DD, BT, DD, 2048, 0, 1, ACT_NONE);
        // topo branch
        mgp(hb, DD, te1T + (size_t)l*32768, DD, te1_b + (size_t)l*PP, nullptr, t1b, PP, BT, PP, DD, 0, 0, ACT_RELU);
        mgp(t1b, PP, te2T + (size_t)l*4096, PP, te2_b + (size_t)l*PP, tf_, tfb, PP, BT, PP, PP, 0, 0, ACT_NONE);
        bd_loss_kernel<<<BT/4, 256, 0, stream>>>(tf_, bd_w + (size_t)l*PP*2, bd_b + (size_t)l*2, out + BB*DIN);
        mgp(tfb, PP, td1T + (size_t)l*32768, PP, td1_b + (size_t)l*DD, nullptr, tdb, DD, BT, DD, PP, 0, 0, ACT_RELU);
        mgp(tdb, DD, td2T + (size_t)l*262144, DD, td2_b + (size_t)l*DD, s_, nullptr, DD, BT, DD, DD, 0, 1, ACT_NONE);
        // causal dilated conv: 3 shifted accumulating GEMMs
        int dil = 1 << l;
        for (int kk = 0; kk < 3; ++kk) {
            int shift = (2 - kk) * dil;
            mgp(hb, DD, ccT + ((size_t)(l*3 + kk))*262144, DD,
                (kk == 2) ? (cc_b + (size_t)l*DD) : nullptr, s_, nullptr, DD, BT, DD, DD, shift, 1, ACT_NONE);
        }
        // h = LN(s + h)
        add_ln_kernel<<<BT/4, 256, 0, stream>>>(s_, h_, hb, ln_g, ln_b);
    }

    // ---- head ----
    build_cat_kernel<<<64, 256, 0, stream>>>(h_, catb);
    sg16_kernel<<<8, 256, 0, stream>>>(catb, mm1_w, mm1_b, tmb, 1024, DD, ACT_TANH,
                                       nullptr, nullptr, nullptr, 0, 0, 0);
    sg16_kernel<<<8, 256, 0, stream>>>(tmb, mm2_w, mm2_b, mixb, DD, DD, ACT_NONE,
                                       nullptr, nullptr, nullptr, 0, 0, 0);
    cur_init_kernel<<<32, 256, 0, stream>>>(h_, mixb, curb);
    for (int t = 0; t < SS; ++t) {
        sg16_kernel<<<8, 256, 0, stream>>>(nullptr, dn1_w, dn1_b, d1b, 1024, DD, ACT_SILU,
                                           curb, noise + (size_t)t*BB*DD, nsched, t, 1, 0);
        sg16_kernel<<<8, 256, 0, stream>>>(d1b, dn2_w, dn2_b, d2b, DD, DD, ACT_SILU,
                                           nullptr, nullptr, nullptr, 0, 0, 0);
        sg16_kernel<<<8, 256, 0, stream>>>(d2b, dn3_w, dn3_b, nullptr, DD, DD, ACT_NONE,
                                           curb, nullptr, nsched, t, 0, 1);
    }
    sg16_kernel<<<6, 256, 0, stream>>>(curb, out_w, out_b, out, DD, DIN, ACT_NONE,
                                       nullptr, nullptr, nullptr, 0, 0, 0);
}

// Round 3
// 2576.634 us; speedup vs baseline: 3.5774x; 1.4369x over previous
//
#include <hip/hip_runtime.h>
#include <hip/hip_bf16.h>
#include <math.h>

#define BB 16
#define TT 256
#define DIN 384
#define DD 512
#define LL 6
#define HH 8
#define PP 64
#define SS 10
#define BT (BB*TT)   // 4096

enum { ACT_NONE=0, ACT_RELU=1, ACT_TANH=2, ACT_SILU=3 };

typedef __attribute__((ext_vector_type(8))) short bf16x8;
typedef __attribute__((ext_vector_type(4))) float f32x4;
typedef __hip_bfloat16 bh16;

typedef const __attribute__((address_space(1))) void gvoid_t;
typedef __attribute__((address_space(3))) void lvoid_t;
__device__ __forceinline__ void gload16(const void* g, void* l) {
    __builtin_amdgcn_global_load_lds((gvoid_t*)g, (lvoid_t*)l, 16, 0, 0);
}

// =====================================================================================
// Generic bf16 MFMA GEMM: C = act(A @ Bt^T + bias)  (Bt stored [N][K])
// BM=128, BN=64, BK=64; 4 waves 2x2, wave tile 64x32 (4x2 frags of 16x16).
// Optional batch dim z: z1=z>>zshift, z0=z&zmask; element-offsets per z1/z0.
// shift: A-row for output row r is (r-shift), valid iff (r%256)>=shift (else zero-page).
// Outputs: Cf fp32 (accum optional) and/or Cb bf16, both ldc.
__global__ __launch_bounds__(256) void mgemm_kernel(
    const bh16* __restrict__ A, int lda,
    const bh16* __restrict__ Bt, int ldb,
    const float* __restrict__ bias,
    float* __restrict__ Cf, bh16* __restrict__ Cb, int ldc,
    int N, int K, int shift, int accum, int act,
    int zmask, int zshift,
    long aS1, long aS0, long bS1, long bS0, long cS1, long cS0,
    const bh16* __restrict__ zp)
{
    __shared__ bf16x8 As[128*8];   // 16KB: [row][8 chunks], chunk XOR-swizzled by row&7
    __shared__ bf16x8 Bs[64*8];    // 8KB

    int z = blockIdx.z;
    long z1 = (long)(z >> zshift), z0 = (long)(z & zmask);
    A  += z1*aS1 + z0*aS0;
    Bt += z1*bS1 + z0*bS0;
    long coff = z1*cS1 + z0*cS0;

    const int tid  = threadIdx.x;
    const int lane = tid & 63, w = tid >> 6;
    const int wm = w >> 1, wn = w & 1;
    const int row0 = blockIdx.y * 128, col0 = blockIdx.x * 64;

    f32x4 acc[4][2];
    #pragma unroll
    for (int i = 0; i < 4; ++i)
        #pragma unroll
        for (int j = 0; j < 2; ++j) acc[i][j] = (f32x4){0.f,0.f,0.f,0.f};

    const int nkt = K >> 6;
    for (int kt = 0; kt < nkt; ++kt) {
        int k0 = kt << 6;
        // stage A: 1024 16B-chunks, 4 instr/wave
        #pragma unroll
        for (int j = 0; j < 4; ++j) {
            int c = ((w*4 + j) << 6) + lane;
            int row = c >> 3, chk = c & 7;
            int schk = chk ^ (row & 7);
            int grow = row0 + row;
            const bh16* src = ((grow & 255) >= shift)
                ? (A + (size_t)(grow - shift)*lda + k0 + schk*8) : zp;
            gload16(src, &As[(w*4 + j) * 64]);
        }
        // stage B: 512 chunks, 2 instr/wave
        #pragma unroll
        for (int j = 0; j < 2; ++j) {
            int c = ((w*2 + j) << 6) + lane;
            int row = c >> 3, chk = c & 7;
            int schk = chk ^ (row & 7);
            int gcol = col0 + row;
            const bh16* src = (gcol < N)
                ? (Bt + (size_t)gcol*ldb + k0 + schk*8) : zp;
            gload16(src, &Bs[(w*2 + j) * 64]);
        }
        asm volatile("s_waitcnt vmcnt(0)" ::: "memory");
        __syncthreads();

        bf16x8 a[4][2], b[2][2];
        #pragma unroll
        for (int fm = 0; fm < 4; ++fm) {
            int row = wm*64 + fm*16 + (lane & 15);
            #pragma unroll
            for (int ks = 0; ks < 2; ++ks)
                a[fm][ks] = As[row*8 + ((ks*4 + (lane>>4)) ^ (row & 7))];
        }
        #pragma unroll
        for (int fn = 0; fn < 2; ++fn) {
            int col = wn*32 + fn*16 + (lane & 15);
            #pragma unroll
            for (int ks = 0; ks < 2; ++ks)
                b[fn][ks] = Bs[col*8 + ((ks*4 + (lane>>4)) ^ (col & 7))];
        }
        #pragma unroll
        for (int ks = 0; ks < 2; ++ks)
            #pragma unroll
            for (int fm = 0; fm < 4; ++fm)
                #pragma unroll
                for (int fn = 0; fn < 2; ++fn)
                    acc[fm][fn] = __builtin_amdgcn_mfma_f32_16x16x32_bf16(
                        a[fm][ks], b[fn][ks], acc[fm][fn], 0, 0, 0);
        __syncthreads();
    }

    // epilogue: D[row][col], col=lane&15, row=(lane>>4)*4+r
    #pragma unroll
    for (int fm = 0; fm < 4; ++fm) {
        #pragma unroll
        for (int fn = 0; fn < 2; ++fn) {
            int gc = col0 + wn*32 + fn*16 + (lane & 15);
            float bs = bias ? bias[gc] : 0.f;
            #pragma unroll
            for (int r = 0; r < 4; ++r) {
                int gr = row0 + wm*64 + fm*16 + (lane>>4)*4 + r;
                float v = acc[fm][fn][r] + bs;
                if (act == ACT_RELU) v = fmaxf(v, 0.f);
                size_t o = (size_t)gr*ldc + gc + coff;
                if (Cf) { if (accum) Cf[o] += v; else Cf[o] = v; }
                if (Cb) Cb[o] = __float2bfloat16(v);
            }
        }
    }
}

// =====================================================================================
// Small-M (M=16) MFMA GEMM, one wave = 16x16xK tile, no LDS.
// out = act(A(16xK) @ Bt^T(NxK) + pre(16xN) + bias(N))
// If curf != null: curf[row*512+col] -= v * (*scaleptr); curb = bf16(curf) (diffusion update).
// Else: Of (f32) and/or Ob (bf16) at z*oZ + row*N + col.
__global__ __launch_bounds__(256) void hgemm16_kernel(
    const bh16* __restrict__ A, int lda, long aZ,
    const bh16* __restrict__ Bt, int ldb,
    const float* __restrict__ bias,
    const float* __restrict__ pre,
    float* __restrict__ Of, bh16* __restrict__ Ob, long oZ,
    int N, int K, int act,
    float* __restrict__ curf, bh16* __restrict__ curb,
    const float* __restrict__ scaleptr)
{
    const int z = blockIdx.z;
    A += (long)z * aZ;
    const int lane = threadIdx.x & 63, w = threadIdx.x >> 6;
    const int col0 = blockIdx.x * 64 + w * 16;
    const int ar = lane & 15;
    const int koff = (lane >> 4) * 8;
    const bh16* arow = A + (size_t)ar * lda + koff;
    const bh16* brow = Bt + (size_t)(col0 + ar) * ldb + koff;
    f32x4 acc = {0.f, 0.f, 0.f, 0.f};
    const int nkt = K >> 5;                 // K multiple of 256 here
    for (int kt0 = 0; kt0 < nkt; kt0 += 8) {
        bf16x8 av[8], bv[8];
        #pragma unroll
        for (int j = 0; j < 8; ++j) {
            av[j] = *(const bf16x8*)(arow + (size_t)(kt0 + j) * 32);
            bv[j] = *(const bf16x8*)(brow + (size_t)(kt0 + j) * 32);
        }
        #pragma unroll
        for (int j = 0; j < 8; ++j)
            acc = __builtin_amdgcn_mfma_f32_16x16x32_bf16(av[j], bv[j], acc, 0, 0, 0);
    }
    const int col = col0 + ar;
    float bs = bias ? bias[col] : 0.f;
    float sc = scaleptr ? *scaleptr : 0.f;
    #pragma unroll
    for (int r = 0; r < 4; ++r) {
        int row = (lane >> 4) * 4 + r;
        float v = acc[r] + bs;
        if (pre) v += pre[(size_t)row * N + col];
        if (act == ACT_SILU)      v = v / (1.f + expf(-v));
        else if (act == ACT_TANH) v = tanhf(v);
        if (curf) {
            size_t o = (size_t)row * 512 + col;
            float nc = curf[o] - v * sc;
            curf[o] = nc;
            curb[o] = __float2bfloat16(nc);
        } else {
            size_t o = (size_t)z * oZ + (size_t)row * N + col;
            if (Of) Of[o] = v;
            if (Ob) Ob[o] = __float2bfloat16(v);
        }
    }
}

// ---------------- per-head squared norms for q and k (bf16 in) ----------------
__global__ __launch_bounds__(256) void sqnorm2_kernel(const bh16* __restrict__ qb, const bh16* __restrict__ kb,
                                                      float* __restrict__ qn, float* __restrict__ kn)
{
    int lane = threadIdx.x & 63, wid = threadIdx.x >> 6;
    int row = blockIdx.x * 4 + wid;            // over B*H*T
    const bh16* src = blockIdx.y ? kb : qb;
    float* dst = blockIdx.y ? kn : qn;
    int t = row & 255; int bh = row >> 8; int b = bh >> 3, hh = bh & 7;
    float v = __bfloat162float(src[((size_t)b * TT + t) * DD + hh * 64 + lane]);
    float s = v * v;
    #pragma unroll
    for (int off = 32; off; off >>= 1) s += __shfl_xor(s, off);
    if (lane == 0) dst[row] = s;
}

// ---------------- hyperbolic distance + softmax: fp32 logits in, bf16 probs out ----------------
__global__ __launch_bounds__(256) void attn_softmax_kernel(const float* __restrict__ at, bh16* __restrict__ pb,
                                                           const float* __restrict__ qn,
                                                           const float* __restrict__ kn,
                                                           const float* __restrict__ curv)
{
    int lane = threadIdx.x & 63, wid = threadIdx.x >> 6;
    int row = blockIdx.x * 4 + wid;            // over B*H*T
    int i = row & 255; int bh = row >> 8; int hh = bh & 7;
    float c = fabsf(curv[hh]) + 1e-8f;
    float inv_sqrt_c = 1.f / sqrtf(c);
    float qni = qn[row];
    const float* srow = at + (size_t)bh * TT * TT + (size_t)i * TT;
    bh16* prow = pb + (size_t)bh * TT * TT + (size_t)i * TT;
    const float* knr = kn + (size_t)bh * TT;
    float logit[4];
    float mx = -1e30f;
    #pragma unroll
    for (int u = 0; u < 4; ++u) {
        int j = lane + u * 64;
        float s = srow[j];
        float knj = knr[j];
        float d2 = fmaxf(qni + knj - 2.f * s, 0.f);
        float denom = fmaxf((1.f - c * qni) * (1.f - c * knj), 1e-5f);
        float arg = fmaxf(1.f + (2.f * c * d2) / denom, 1.00001f);
        float dist = logf(arg + sqrtf((arg - 1.f) * (arg + 1.f))) * inv_sqrt_c;
        logit[u] = -dist;
        mx = fmaxf(mx, logit[u]);
    }
    #pragma unroll
    for (int off = 32; off; off >>= 1) mx = fmaxf(mx, __shfl_xor(mx, off));
    float e[4]; float sum = 0.f;
    #pragma unroll
    for (int u = 0; u < 4; ++u) { e[u] = expf(logit[u] - mx); sum += e[u]; }
    #pragma unroll
    for (int off = 32; off; off >>= 1) sum += __shfl_xor(sum, off);
    float inv = 1.f / sum;
    #pragma unroll
    for (int u = 0; u < 4; ++u) prow[lane + u * 64] = __float2bfloat16(e[u] * inv);
}

// ---------------- V transpose per (b,h): vb[b][t][h*64+d] -> vt[bh][d][t] ----------------
__global__ __launch_bounds__(256) void vtrans_kernel(const bh16* __restrict__ vb, bh16* __restrict__ vt)
{
    int bh = blockIdx.y, b = bh >> 3, hh = bh & 7;
    int t0 = blockIdx.x * 64;
    __shared__ bh16 tile[64][65];
    for (int e = threadIdx.x; e < 4096; e += 256) {
        int r = e >> 6, c = e & 63;
        tile[r][c] = vb[((size_t)(b*256 + t0 + r))*512 + hh*64 + c];
    }
    __syncthreads();
    for (int e = threadIdx.x; e < 4096; e += 256) {
        int d = e >> 6, t2 = e & 63;
        vt[((size_t)bh*64 + d)*256 + t0 + t2] = tile[t2][d];
    }
}

// ---------------- wavelet filter softmax ----------------
__global__ __launch_bounds__(256) void filt_softmax_kernel(const float* __restrict__ w0, const float* __restrict__ w1,
                                                           const float* __restrict__ w2, const float* __restrict__ w3,
                                                           float* __restrict__ filt)
{
    int idx = blockIdx.x * 256 + threadIdx.x;
    if (idx >= 4 * DD) return;
    int d = idx & 511, i = idx >> 9;
    const float* w = (i == 0) ? w0 : (i == 1) ? w1 : (i == 2) ? w2 : w3;
    int K = 4 << i;
    int fb = (i == 0) ? 0 : (i == 1) ? 2048 : (i == 2) ? 6144 : 14336;
    const float* row = w + (size_t)d * K;
    float mx = -1e30f;
    for (int k = 0; k < K; ++k) mx = fmaxf(mx, row[k]);
    float s = 0.f;
    for (int k = 0; k < K; ++k) s += expf(row[k] - mx);
    float inv = 1.f / s;
    float* fo = filt + fb + (size_t)d * K;
    for (int k = 0; k < K; ++k) fo[k] = expf(row[k] - mx) * inv;
}

// ---------------- all 4 wavelet decompositions fused ----------------
__global__ __launch_bounds__(256) void wdec_kernel(const float* __restrict__ h, const float* __restrict__ filt,
                                                   float* __restrict__ dec)
{
    int idx = blockIdx.x * 256 + threadIdx.x;   // < 1966080
    int i, base;
    if (idx < 1048576)      { i = 0; base = 0; }
    else if (idx < 1572864) { i = 1; base = 1048576; }
    else if (idx < 1835008) { i = 2; base = 1572864; }
    else                    { i = 3; base = 1835008; }
    int loc = idx - base;
    int K = 4 << i, stride = 2 << i, lgTi = 7 - i, Ti = 128 >> i;
    const int fbarr[4] = {0, 2048, 6144, 14336};
    int d = loc & 511; int rem = loc >> 9; int j = rem & (Ti - 1); int b = rem >> lgTi;
    const float* frow = filt + fbarr[i] + (size_t)d * K;
    int tbase = j * stride - (K - 1);
    float acc = 0.f;
    for (int k = 0; k < K; ++k) {
        int t = tbase + k;
        if (t >= 0) acc += h[((size_t)b * TT + t) * DD + d] * frow[k];
    }
    dec[idx] = acc;
}

// ---------------- linear interp back to T: comb (B,T,4D) bf16 ----------------
__global__ __launch_bounds__(256) void winterp_kernel(const float* __restrict__ dec, bh16* __restrict__ comb)
{
    int idx = blockIdx.x * 256 + threadIdx.x;   // over B*T*2048
    int col = idx & 2047; int rem = idx >> 11; int t = rem & 255; int b = rem >> 8;
    if (b >= BB) return;
    int i = col >> 9, d = col & 511;
    int Ti = 256 >> (i + 1);
    const size_t offs[4] = {0, 1048576, 1572864, 1835008};
    float pos = ((float)t + 0.5f) * ((float)Ti / 256.f) - 0.5f;
    pos = fminf(fmaxf(pos, 0.f), (float)(Ti - 1));
    int lo = (int)floorf(pos);
    int hi = min(lo + 1, Ti - 1);
    float w = pos - (float)lo;
    const float* db = dec + offs[i] + (size_t)b * Ti * DD;
    float vlo = db[(size_t)lo * DD + d], vhi = db[(size_t)hi * DD + d];
    comb[idx] = __float2bfloat16(vlo * (1.f - w) + vhi * w);
}

// ---------------- boundary loss ----------------
__global__ __launch_bounds__(256) void bd_loss_kernel(const float* __restrict__ tfb, const float* __restrict__ bdw,
                                                      const float* __restrict__ bdb, float* __restrict__ loss)
{
    int lane = threadIdx.x & 63, wid = threadIdx.x >> 6;
    int row = blockIdx.x * 4 + wid;   // over BT
    float w = bdw[lane * 2] - bdw[lane * 2 + 1];
    float vv = tfb[(size_t)row * PP + lane] * w;
    #pragma unroll
    for (int off = 32; off; off >>= 1) vv += __shfl_xor(vv, off);
    if (lane == 0) {
        float xv = vv + (bdb[0] - bdb[1]) + 0.1f;
        atomicAdd(loss, fmaxf(xv, 0.f) * (1.f / 4096.f));
    }
}

// ---------------- h = layernorm(s + h)*g + b, dual fp32+bf16 out ----------------
__global__ __launch_bounds__(256) void add_ln_kernel(const float* __restrict__ s, float* __restrict__ h,
                                                     bh16* __restrict__ hb,
                                                     const float* __restrict__ g, const float* __restrict__ be)
{
    int lane = threadIdx.x & 63, wid = threadIdx.x >> 6;
    size_t row = (size_t)blockIdx.x * 4 + wid;
    const float* sr = s + row * DD;
    float* hr = h + row * DD;
    bh16* hbr = hb + row * DD;
    float xv[8]; float sum = 0.f;
    #pragma unroll
    for (int u = 0; u < 8; ++u) { int c = lane + u * 64; xv[u] = sr[c] + hr[c]; sum += xv[u]; }
    #pragma unroll
    for (int off = 32; off; off >>= 1) sum += __shfl_xor(sum, off);
    float mu = sum * (1.f / 512.f);
    float sq = 0.f;
    #pragma unroll
    for (int u = 0; u < 8; ++u) { float d = xv[u] - mu; sq += d * d; }
    #pragma unroll
    for (int off = 32; off; off >>= 1) sq += __shfl_xor(sq, off);
    float rstd = 1.f / sqrtf(sq * (1.f / 512.f) + 1e-5f);
    #pragma unroll
    for (int u = 0; u < 8; ++u) {
        int c = lane + u * 64;
        float v = (xv[u] - mu) * rstd * g[c] + be[c];
        hr[c] = v;
        hbr[c] = __float2bfloat16(v);
    }
}

// ---------------- weight transpose-convert: [L][K][N] f32 -> [L][N][K] bf16 ----------------
__global__ __launch_bounds__(256) void wtrans_kernel(const float* __restrict__ W, bh16* __restrict__ Wt,
                                                     int K, int N)
{
    int l = blockIdx.z;
    const float* Wl = W + (size_t)l * K * N;
    bh16* Wo = Wt + (size_t)l * N * K;
    __shared__ float tile[32][33];
    int n0 = blockIdx.x * 32, k0 = blockIdx.y * 32;
    int lx = threadIdx.x & 31, ly = threadIdx.x >> 5;
    #pragma unroll
    for (int j = 0; j < 4; ++j) {
        int kk = ly + j * 8;
        tile[kk][lx] = Wl[(size_t)(k0 + kk) * N + n0 + lx];
    }
    __syncthreads();
    #pragma unroll
    for (int j = 0; j < 4; ++j) {
        int nr = ly + j * 8;
        Wo[(size_t)(n0 + nr) * K + k0 + lx] = __float2bfloat16(tile[lx][nr]);
    }
}

// ---------------- cc_w [L][O][I][3] f32 -> ccT [L][3][O][I] bf16 ----------------
__global__ __launch_bounds__(256) void ccconv_kernel(const float* __restrict__ ccw, bh16* __restrict__ ccT)
{
    size_t idx = (size_t)blockIdx.x * 256 + threadIdx.x;   // 6*3*512*512
    int i = idx & 511; size_t rem = idx >> 9;
    int o = rem & 511; rem >>= 9;
    int k = (int)(rem % 3); int l = (int)(rem / 3);
    ccT[idx] = __float2bfloat16(ccw[(((size_t)l*512 + o)*512 + i)*3 + k]);
}

// ---------------- x f32 -> bf16 ----------------
__global__ __launch_bounds__(256) void convx_kernel(const float* __restrict__ x, bh16* __restrict__ xb)
{
    size_t idx = (size_t)blockIdx.x * 256 + threadIdx.x;
    xb[idx] = __float2bfloat16(x[idx]);
}

// ---------------- E matrix: row (t,b) = [sched[t]*noise[t,b,:] | temb[t]] (bf16, 160x1024) ----------------
__global__ __launch_bounds__(256) void build_E_kernel(const float* __restrict__ noise, const float* __restrict__ sched,
                                                      bh16* __restrict__ E)
{
    int idx = blockIdx.x * 256 + threadIdx.x;   // 10*16*1024
    if (idx >= SS * BB * 1024) return;
    int k = idx & 1023; int rem = idx >> 10; int b = rem & 15; int t = rem >> 4;
    float v;
    if (k < 512) {
        v = sched[t] * noise[((size_t)t * BB + b) * 512 + k];
    } else {
        int j = k - 512;
        const float kfac = -9.210340371976184f / 255.f;   // -ln(10000)/255
        v = (j < 256) ? sinf((float)t * expf((float)j * kfac))
                      : cosf((float)t * expf((float)(j - 256) * kfac));
    }
    E[idx] = __float2bfloat16(v);
}

// ---------------- head helpers ----------------
__global__ void init_kernel(bh16* zp, float* loss)
{
    int t = threadIdx.x;
    if (t < 64) zp[t] = __float2bfloat16(0.f);
    if (t == 64) *loss = 0.f;
}

__global__ __launch_bounds__(256) void build_cat16_kernel(const float* __restrict__ h, bh16* __restrict__ catb)
{
    int idx = blockIdx.x * 256 + threadIdx.x;   // 16*1024
    if (idx >= BB * 1024) return;
    int k = idx & 1023, b = idx >> 10;
    float v = (k < 512) ? h[((size_t)b * TT + 255) * DD + k]
                        : h[((size_t)b * TT + 254) * DD + (k - 512)];
    catb[idx] = __float2bfloat16(v);
}

__global__ __launch_bounds__(256) void cur_init2_kernel(const float* __restrict__ h, const float* __restrict__ mix,
                                                        float* __restrict__ curf, bh16* __restrict__ curb)
{
    int idx = blockIdx.x * 256 + threadIdx.x;   // 16*512
    if (idx >= BB * DD) return;
    int c = idx & 511, b = idx >> 9;
    float v = h[((size_t)b * TT + 255) * DD + c] + mix[idx];
    curf[idx] = v;
    curb[idx] = __float2bfloat16(v);
}

__global__ void fail_kernel(float* p) { p[0] = 1e30f; }

// =====================================================================================
extern "C" void kernel_launch(void* const* d_in, const int* in_sizes, int n_in,
                              void* d_out, int out_size, void* d_ws, size_t ws_size,
                              hipStream_t stream)
{
    const float* x      = (const float*)d_in[0];
    const float* in_w   = (const float*)d_in[1];
    const float* in_b   = (const float*)d_in[2];
    const float* gq_w   = (const float*)d_in[3];
    const float* gq_b   = (const float*)d_in[4];
    const float* gk_w   = (const float*)d_in[5];
    const float* gk_b   = (const float*)d_in[6];
    const float* gv_w   = (const float*)d_in[7];
    const float* gv_b   = (const float*)d_in[8];
    const float* go_w   = (const float*)d_in[9];
    const float* go_b   = (const float*)d_in[10];
    const float* curv   = (const float*)d_in[11];
    const float* wav0   = (const float*)d_in[12];
    const float* wav1   = (const float*)d_in[13];
    const float* wav2   = (const float*)d_in[14];
    const float* wav3   = (const float*)d_in[15];
    const float* wrec_w = (const float*)d_in[16];
    const float* wrec_b = (const float*)d_in[17];
    const float* te1_w  = (const float*)d_in[18];
    const float* te1_b  = (const float*)d_in[19];
    const float* te2_w  = (const float*)d_in[20];
    const float* te2_b  = (const float*)d_in[21];
    const float* td1_w  = (const float*)d_in[22];
    const float* td1_b  = (const float*)d_in[23];
    const float* td2_w  = (const float*)d_in[24];
    const float* td2_b  = (const float*)d_in[25];
    const float* bd_w   = (const float*)d_in[26];
    const float* bd_b   = (const float*)d_in[27];
    const float* cc_w   = (const float*)d_in[28];
    const float* cc_b   = (const float*)d_in[29];
    const float* ln_g   = (const float*)d_in[30];
    const float* ln_b   = (const float*)d_in[31];
    const float* mm1_w  = (const float*)d_in[32];
    const float* mm1_b  = (const float*)d_in[33];
    const float* mm2_w  = (const float*)d_in[34];
    const float* mm2_b  = (const float*)d_in[35];
    const float* dn1_w  = (const float*)d_in[36];
    const float* dn1_b  = (const float*)d_in[37];
    const float* dn2_w  = (const float*)d_in[38];
    const float* dn2_b  = (const float*)d_in[39];
    const float* dn3_w  = (const float*)d_in[40];
    const float* dn3_b  = (const float*)d_in[41];
    const float* out_w  = (const float*)d_in[42];
    const float* out_b  = (const float*)d_in[43];
    const float* nsched = (const float*)d_in[44];
    const float* noise  = (const float*)d_in[45];
    float* out = (float*)d_out;
    float* ws  = (float*)d_ws;

    // ---- fp32 workspace layout (float offsets) ----
    const size_t o_h   = 0;          // 2097152
    const size_t o_dec = 2097152;    // 2097152 (also pre1 for head: 81920)
    const size_t o_s   = 4194304;    // 2097152
    const size_t o_tf  = 6291456;    // 262144
    const size_t o_qn  = 6553600;    // 32768
    const size_t o_kn  = 6586368;    // 32768
    const size_t o_at  = 6619136;    // 8388608
    const size_t o_fl  = 15007744;   // 30720
    const size_t o_mix = 15038464;   // 8192
    const size_t o_cur = 15046656;   // 8192
    const size_t FP32_TOTAL = 15095808;
    // ---- bf16 region (element offsets from bp) ----
    const size_t b_xb   = 0;          // 1572864
    const size_t b_hb   = 1572864;    // 2097152
    const size_t b_qb   = 3670016;
    const size_t b_kb   = 5767168;
    const size_t b_vb   = 7864320;
    const size_t b_vt   = 9961472;
    const size_t b_pb   = 12058624;   // 8388608 (head scratch aliases here after layers)
    const size_t b_gmb  = 20447232;
    const size_t b_tdb  = 22544384;
    const size_t b_t1b  = 24641536;   // 262144
    const size_t b_tfb  = 24903680;   // 262144
    const size_t b_zp   = 25165824;   // 512
    const size_t b_inwT = 25166336;   // 196608
    const size_t b_gqT  = 25362944;   // 1572864
    const size_t b_gkT  = 26935808;
    const size_t b_gvT  = 28508672;
    const size_t b_goT  = 30081536;
    const size_t b_wrT  = 31654400;   // 6291456
    const size_t b_td1T = 37945856;   // 196608
    const size_t b_td2T = 38142464;   // 1572864
    const size_t b_te1T = 39715328;   // 196608
    const size_t b_te2T = 39911936;   // 24576
    const size_t b_ccT  = 39936512;   // 4718592
    const size_t BF16_TOTAL = 44655104;
    const size_t TOTAL_BYTES = FP32_TOTAL * 4 + BF16_TOTAL * 2;
    if (ws_size < TOTAL_BYTES) { fail_kernel<<<1, 1, 0, stream>>>(out); return; }

    float* h_   = ws + o_h;
    float* dec_ = ws + o_dec;
    float* s_   = ws + o_s;
    float* tf_  = ws + o_tf;
    float* qn_  = ws + o_qn;
    float* kn_  = ws + o_kn;
    float* at_  = ws + o_at;
    float* fl_  = ws + o_fl;
    float* mixb = ws + o_mix;
    float* curf = ws + o_cur;
    bh16* bp   = (bh16*)(ws + FP32_TOTAL);
    bh16* xb   = bp + b_xb;
    bh16* hb   = bp + b_hb;
    bh16* qb   = bp + b_qb;
    bh16* kb   = bp + b_kb;
    bh16* vb   = bp + b_vb;
    bh16* vt   = bp + b_vt;
    bh16* pb   = bp + b_pb;
    bh16* gmb  = bp + b_gmb;
    bh16* tdb  = bp + b_tdb;
    bh16* t1b  = bp + b_t1b;
    bh16* tfb  = bp + b_tfb;
    bh16* zp   = bp + b_zp;
    bh16* inwT = bp + b_inwT;
    bh16* gqT  = bp + b_gqT;
    bh16* gkT  = bp + b_gkT;
    bh16* gvT  = bp + b_gvT;
    bh16* goT  = bp + b_goT;
    bh16* wrT  = bp + b_wrT;
    bh16* td1T = bp + b_td1T;
    bh16* td2T = bp + b_td2T;
    bh16* te1T = bp + b_te1T;
    bh16* te2T = bp + b_te2T;
    bh16* ccT  = bp + b_ccT;
    bh16* combb = (bh16*)at_;   // aliases at_ after softmax consumed it

    // head bf16 scratch: aliased into pb region (dead after layer loop)
    bh16* dn1T  = pb;             // 524288
    bh16* dn2T  = pb + 524288;    // 262144
    bh16* dn3T  = pb + 786432;    // 262144
    bh16* mm1T  = pb + 1048576;   // 524288
    bh16* mm2T  = pb + 1572864;   // 262144
    bh16* outT  = pb + 1835008;   // 196608
    bh16* E16   = pb + 2031616;   // 163840
    bh16* cat16 = pb + 2195456;   // 16384
    bh16* tmb16 = pb + 2211840;   // 8192
    bh16* cur16 = pb + 2220032;   // 8192
    bh16* d1b16 = pb + 2228224;   // 8192
    bh16* d2b16 = pb + 2236416;   // 8192
    float* pre1 = dec_;           // 81920 f32, aliases dec_ after layers

    auto mg = [&](const bh16* A, int lda, const bh16* Bt, int ldb,
                  const float* bias, float* Cf, bh16* Cb, int ldc,
                  int M, int N, int K, int shift, int accum, int act,
                  int nb, int zmask, int zshift,
                  long aS1, long aS0, long bS1, long bS0, long cS1, long cS0) {
        dim3 g(N / 64, M / 128, nb);
        mgemm_kernel<<<g, 256, 0, stream>>>(A, lda, Bt, ldb, bias, Cf, Cb, ldc, N, K,
                                            shift, accum, act, zmask, zshift,
                                            aS1, aS0, bS1, bS0, cS1, cS0, zp);
    };
    auto mgp = [&](const bh16* A, int lda, const bh16* Bt, int ldb,
                   const float* bias, float* Cf, bh16* Cb, int ldc,
                   int M, int N, int K, int shift, int accum, int act) {
        mg(A, lda, Bt, ldb, bias, Cf, Cb, ldc, M, N, K, shift, accum, act, 1, 0, 0, 0, 0, 0, 0, 0, 0);
    };
    auto hg = [&](const bh16* A, int lda, long aZ, const bh16* Bt, int ldb,
                  const float* bias, const float* pre, float* Of, bh16* Ob, long oZ,
                  int N, int K, int act, float* cf, bh16* cb, const float* sp, int nz) {
        hgemm16_kernel<<<dim3(N / 64, 1, nz), 256, 0, stream>>>(
            A, lda, aZ, Bt, ldb, bias, pre, Of, Ob, oZ, N, K, act, cf, cb, sp);
    };

    // ---- setup: zero page/loss, converts ----
    init_kernel<<<1, 128, 0, stream>>>(zp, out + BB * DIN);
    convx_kernel<<<BT * DIN / 256, 256, 0, stream>>>(x, xb);
    wtrans_kernel<<<dim3(DD/32, DIN/32, 1), 256, 0, stream>>>(in_w, inwT, DIN, DD);
    wtrans_kernel<<<dim3(16, 16, 6), 256, 0, stream>>>(gq_w, gqT, DD, DD);
    wtrans_kernel<<<dim3(16, 16, 6), 256, 0, stream>>>(gk_w, gkT, DD, DD);
    wtrans_kernel<<<dim3(16, 16, 6), 256, 0, stream>>>(gv_w, gvT, DD, DD);
    wtrans_kernel<<<dim3(16, 16, 6), 256, 0, stream>>>(go_w, goT, DD, DD);
    wtrans_kernel<<<dim3(16, 64, 6), 256, 0, stream>>>(wrec_w, wrT, 2048, DD);
    wtrans_kernel<<<dim3(16, 2, 6), 256, 0, stream>>>(td1_w, td1T, PP, DD);
    wtrans_kernel<<<dim3(16, 16, 6), 256, 0, stream>>>(td2_w, td2T, DD, DD);
    wtrans_kernel<<<dim3(2, 16, 6), 256, 0, stream>>>(te1_w, te1T, DD, PP);
    wtrans_kernel<<<dim3(2, 2, 6), 256, 0, stream>>>(te2_w, te2T, PP, PP);
    ccconv_kernel<<<18432, 256, 0, stream>>>(cc_w, ccT);

    // h = x @ in_w + in_b  (fp32 + bf16)
    mgp(xb, DIN, inwT, DIN, in_b, h_, hb, DD, BT, DD, DIN, 0, 0, ACT_NONE);

    for (int l = 0; l < LL; ++l) {
        // q, k, v (bf16 only)
        mgp(hb, DD, gqT + (size_t)l*262144, DD, gq_b + (size_t)l*DD, nullptr, qb, DD, BT, DD, DD, 0, 0, ACT_NONE);
        mgp(hb, DD, gkT + (size_t)l*262144, DD, gk_b + (size_t)l*DD, nullptr, kb, DD, BT, DD, DD, 0, 0, ACT_NONE);
        mgp(hb, DD, gvT + (size_t)l*262144, DD, gv_b + (size_t)l*DD, nullptr, vb, DD, BT, DD, DD, 0, 0, ACT_NONE);
        // attention
        sqnorm2_kernel<<<dim3(8192, 2), 256, 0, stream>>>(qb, kb, qn_, kn_);
        mg(qb, DD, kb, DD, nullptr, at_, nullptr, TT, TT, TT, 64, 0, 0, ACT_NONE,
           128, 7, 3, 131072, 64, 131072, 64, 524288, 65536);
        attn_softmax_kernel<<<8192, 256, 0, stream>>>(at_, pb, qn_, kn_, curv + (size_t)l*HH);
        vtrans_kernel<<<dim3(4, 128), 256, 0, stream>>>(vb, vt);
        mg(pb, TT, vt, TT, nullptr, nullptr, gmb, DD, TT, 64, TT, 0, 0, ACT_NONE,
           128, 7, 3, 524288, 65536, 131072, 16384, 131072, 64);
        mgp(gmb, DD, goT + (size_t)l*262144, DD, go_b + (size_t)l*DD, s_, nullptr, DD, BT, DD, DD, 0, 0, ACT_NONE);
        // wavelet branch
        filt_softmax_kernel<<<8, 256, 0, stream>>>(wav0 + (size_t)l*DD*4, wav1 + (size_t)l*DD*8,
                                                   wav2 + (size_t)l*DD*16, wav3 + (size_t)l*DD*32, fl_);
        wdec_kernel<<<7680, 256, 0, stream>>>(h_, fl_, dec_);
        winterp_kernel<<<(BT * 2048) / 256, 256, 0, stream>>>(dec_, combb);
        mgp(combb, 2048, wrT + (size_t)l*1048576, 2048, wrec_b + (size_t)l*DD, s_, nullptr, DD, BT, DD, 2048, 0, 1, ACT_NONE);
        // topo branch
        mgp(hb, DD, te1T + (size_t)l*32768, DD, te1_b + (size_t)l*PP, nullptr, t1b, PP, BT, PP, DD, 0, 0, ACT_RELU);
        mgp(t1b, PP, te2T + (size_t)l*4096, PP, te2_b + (size_t)l*PP, tf_, tfb, PP, BT, PP, PP, 0, 0, ACT_NONE);
        bd_loss_kernel<<<BT/4, 256, 0, stream>>>(tf_, bd_w + (size_t)l*PP*2, bd_b + (size_t)l*2, out + BB*DIN);
        mgp(tfb, PP, td1T + (size_t)l*32768, PP, td1_b + (size_t)l*DD, nullptr, tdb, DD, BT, DD, PP, 0, 0, ACT_RELU);
        mgp(tdb, DD, td2T + (size_t)l*262144, DD, td2_b + (size_t)l*DD, s_, nullptr, DD, BT, DD, DD, 0, 1, ACT_NONE);
        // causal dilated conv: 3 shifted accumulating GEMMs
        int dil = 1 << l;
        for (int kk = 0; kk < 3; ++kk) {
            int shift = (2 - kk) * dil;
            mgp(hb, DD, ccT + ((size_t)(l*3 + kk))*262144, DD,
                (kk == 2) ? (cc_b + (size_t)l*DD) : nullptr, s_, nullptr, DD, BT, DD, DD, shift, 1, ACT_NONE);
        }
        // h = LN(s + h)
        add_ln_kernel<<<BT/4, 256, 0, stream>>>(s_, h_, hb, ln_g, ln_b);
    }

    // ---- head: convert weights (into dead pb region), precompute E/pre1 ----
    wtrans_kernel<<<dim3(16, 32, 1), 256, 0, stream>>>(dn1_w, dn1T, 1024, 512);
    wtrans_kernel<<<dim3(16, 16, 1), 256, 0, stream>>>(dn2_w, dn2T, 512, 512);
    wtrans_kernel<<<dim3(16, 16, 1), 256, 0, stream>>>(dn3_w, dn3T, 512, 512);
    wtrans_kernel<<<dim3(16, 32, 1), 256, 0, stream>>>(mm1_w, mm1T, 1024, 512);
    wtrans_kernel<<<dim3(16, 16, 1), 256, 0, stream>>>(mm2_w, mm2T, 512, 512);
    wtrans_kernel<<<dim3(12, 16, 1), 256, 0, stream>>>(out_w, outT, 512, 384);
    build_E_kernel<<<640, 256, 0, stream>>>(noise, nsched, E16);
    // pre1[t] = E_t @ dn1_w + dn1_b   (z-batched over t)
    hg(E16, 1024, 16*1024, dn1T, 1024, dn1_b, nullptr, pre1, nullptr, 8192,
       512, 1024, ACT_NONE, nullptr, nullptr, nullptr, SS);
    // mix head
    build_cat16_kernel<<<64, 256, 0, stream>>>(h_, cat16);
    hg(cat16, 1024, 0, mm1T, 1024, mm1_b, nullptr, nullptr, tmb16, 0,
       512, 1024, ACT_TANH, nullptr, nullptr, nullptr, 1);
    hg(tmb16, 512, 0, mm2T, 512, mm2_b, nullptr, mixb, nullptr, 0,
       512, 512, ACT_NONE, nullptr, nullptr, nullptr, 1);
    cur_init2_kernel<<<32, 256, 0, stream>>>(h_, mixb, curf, cur16);
    // diffusion chain: 3 launches per step
    for (int t = 0; t < SS; ++t) {
        hg(cur16, 512, 0, dn1T, 1024, nullptr, pre1 + (size_t)t*8192, nullptr, d1b16, 0,
           512, 512, ACT_SILU, nullptr, nullptr, nullptr, 1);
        hg(d1b16, 512, 0, dn2T, 512, dn2_b, nullptr, nullptr, d2b16, 0,
           512, 512, ACT_SILU, nullptr, nullptr, nullptr, 1);
        hg(d2b16, 512, 0, dn3T, 512, dn3_b, nullptr, nullptr, nullptr, 0,
           512, 512, ACT_NONE, curf, cur16, nsched + t, 1);
    }
    // pred = cur @ out_w + out_b
    hg(cur16, 512, 0, outT, 512, out_b, nullptr, out, nullptr, 0,
       384, 512, ACT_NONE, nullptr, nullptr, nullptr, 1);
}

// Round 5
// 2083.134 us; speedup vs baseline: 4.4248x; 1.2369x over previous
//
#include <hip/hip_runtime.h>
#include <hip/hip_bf16.h>
#include <math.h>

#define BB 16
#define TT 256
#define DIN 384
#define DD 512
#define LL 6
#define HH 8
#define PP 64
#define SS 10
#define BT (BB*TT)   // 4096

enum { ACT_NONE=0, ACT_RELU=1, ACT_TANH=2, ACT_SILU=3 };

typedef __attribute__((ext_vector_type(8))) short bf16x8;
typedef __attribute__((ext_vector_type(4))) float f32x4;
typedef __hip_bfloat16 bh16;

typedef const __attribute__((address_space(1))) void gvoid_t;
typedef __attribute__((address_space(3))) void lvoid_t;
__device__ __forceinline__ void gload16(const void* g, void* l) {
    __builtin_amdgcn_global_load_lds((gvoid_t*)g, (lvoid_t*)l, 16, 0, 0);
}

// =====================================================================================
// Generic bf16 MFMA GEMM: C = act(A @ Bt^T + bias)  (Bt stored [N][K])
// BM=128, BN=64, BK=64; 4 waves 2x2, wave tile 64x32 (4x2 frags of 16x16).
// Optional batch dim z: z1=z>>zshift, z0=z&zmask; element-offsets per z1/z0.
// shift: A-row for output row r is (r-shift), valid iff (r%256)>=shift (else zero-page).
// ccdil: fused 3-tap causal conv over packed K=1536 (A lda=512, row-aliased):
//   tap = kt/8; mask threshold (2-tap)*ccdil; address shift mask+tap so that
//   (grow-addr_sh)*512 + tap*512 + c == (grow-mask_sh)*512 + c  (the desired tap row).
// Outputs: Cf fp32 (accum optional) and/or Cb bf16, both ldc.
__global__ __launch_bounds__(256) void mgemm_kernel(
    const bh16* __restrict__ A, int lda,
    const bh16* __restrict__ Bt, int ldb,
    const float* __restrict__ bias,
    float* __restrict__ Cf, bh16* __restrict__ Cb, int ldc,
    int N, int K, int shift, int accum, int act,
    int zmask, int zshift,
    long aS1, long aS0, long bS1, long bS0, long cS1, long cS0,
    int ccdil,
    const bh16* __restrict__ zp)
{
    __shared__ bf16x8 As[128*8];   // 16KB: [row][8 chunks], chunk XOR-swizzled by row&7
    __shared__ bf16x8 Bs[64*8];    // 8KB

    int z = blockIdx.z;
    long z1 = (long)(z >> zshift), z0 = (long)(z & zmask);
    A  += z1*aS1 + z0*aS0;
    Bt += z1*bS1 + z0*bS0;
    long coff = z1*cS1 + z0*cS0;

    const int tid  = threadIdx.x;
    const int lane = tid & 63, w = tid >> 6;
    const int wm = w >> 1, wn = w & 1;
    const int row0 = blockIdx.y * 128, col0 = blockIdx.x * 64;

    f32x4 acc[4][2];
    #pragma unroll
    for (int i = 0; i < 4; ++i)
        #pragma unroll
        for (int j = 0; j < 2; ++j) acc[i][j] = (f32x4){0.f,0.f,0.f,0.f};

    const int nkt = K >> 6;
    for (int kt = 0; kt < nkt; ++kt) {
        int k0 = kt << 6;
        int mask_sh, addr_sh;
        if (ccdil) {
            int tap = kt >> 3;
            mask_sh = (2 - tap) * ccdil;
            addr_sh = mask_sh + tap;      // compensates k0 row-aliasing (lda=512, k0 carries tap*512)
        } else {
            mask_sh = shift; addr_sh = shift;
        }
        // stage A: 1024 16B-chunks, 4 instr/wave
        #pragma unroll
        for (int j = 0; j < 4; ++j) {
            int c = ((w*4 + j) << 6) + lane;
            int row = c >> 3, chk = c & 7;
            int schk = chk ^ (row & 7);
            int grow = row0 + row;
            const bh16* src = ((grow & 255) >= mask_sh)
                ? (A + (size_t)(grow - addr_sh)*lda + k0 + schk*8) : zp;
            gload16(src, &As[(w*4 + j) * 64]);
        }
        // stage B: 512 chunks, 2 instr/wave
        #pragma unroll
        for (int j = 0; j < 2; ++j) {
            int c = ((w*2 + j) << 6) + lane;
            int row = c >> 3, chk = c & 7;
            int schk = chk ^ (row & 7);
            int gcol = col0 + row;
            const bh16* src = (gcol < N)
                ? (Bt + (size_t)gcol*ldb + k0 + schk*8) : zp;
            gload16(src, &Bs[(w*2 + j) * 64]);
        }
        asm volatile("s_waitcnt vmcnt(0)" ::: "memory");
        __syncthreads();

        bf16x8 a[4][2], b[2][2];
        #pragma unroll
        for (int fm = 0; fm < 4; ++fm) {
            int row = wm*64 + fm*16 + (lane & 15);
            #pragma unroll
            for (int ks = 0; ks < 2; ++ks)
                a[fm][ks] = As[row*8 + ((ks*4 + (lane>>4)) ^ (row & 7))];
        }
        #pragma unroll
        for (int fn = 0; fn < 2; ++fn) {
            int col = wn*32 + fn*16 + (lane & 15);
            #pragma unroll
            for (int ks = 0; ks < 2; ++ks)
                b[fn][ks] = Bs[col*8 + ((ks*4 + (lane>>4)) ^ (col & 7))];
        }
        #pragma unroll
        for (int ks = 0; ks < 2; ++ks)
            #pragma unroll
            for (int fm = 0; fm < 4; ++fm)
                #pragma unroll
                for (int fn = 0; fn < 2; ++fn)
                    acc[fm][fn] = __builtin_amdgcn_mfma_f32_16x16x32_bf16(
                        a[fm][ks], b[fn][ks], acc[fm][fn], 0, 0, 0);
        __syncthreads();
    }

    // epilogue: D[row][col], col=lane&15, row=(lane>>4)*4+r
    #pragma unroll
    for (int fm = 0; fm < 4; ++fm) {
        #pragma unroll
        for (int fn = 0; fn < 2; ++fn) {
            int gc = col0 + wn*32 + fn*16 + (lane & 15);
            float bs = bias ? bias[gc] : 0.f;
            #pragma unroll
            for (int r = 0; r < 4; ++r) {
                int gr = row0 + wm*64 + fm*16 + (lane>>4)*4 + r;
                float v = acc[fm][fn][r] + bs;
                if (act == ACT_RELU) v = fmaxf(v, 0.f);
                size_t o = (size_t)gr*ldc + gc + coff;
                if (Cf) { if (accum) Cf[o] += v; else Cf[o] = v; }
                if (Cb) Cb[o] = __float2bfloat16(v);
            }
        }
    }
}

// =====================================================================================
// Small-M (M=16) MFMA GEMM, one wave = 16x16xK tile, no LDS.
__global__ __launch_bounds__(256) void hgemm16_kernel(
    const bh16* __restrict__ A, int lda, long aZ,
    const bh16* __restrict__ Bt, int ldb,
    const float* __restrict__ bias,
    const float* __restrict__ pre,
    float* __restrict__ Of, bh16* __restrict__ Ob, long oZ,
    int N, int K, int act,
    float* __restrict__ curf, bh16* __restrict__ curb,
    const float* __restrict__ scaleptr)
{
    const int z = blockIdx.z;
    A += (long)z * aZ;
    const int lane = threadIdx.x & 63, w = threadIdx.x >> 6;
    const int col0 = blockIdx.x * 64 + w * 16;
    const int ar = lane & 15;
    const int koff = (lane >> 4) * 8;
    const bh16* arow = A + (size_t)ar * lda + koff;
    const bh16* brow = Bt + (size_t)(col0 + ar) * ldb + koff;
    f32x4 acc = {0.f, 0.f, 0.f, 0.f};
    const int nkt = K >> 5;
    for (int kt0 = 0; kt0 < nkt; kt0 += 8) {
        bf16x8 av[8], bv[8];
        #pragma unroll
        for (int j = 0; j < 8; ++j) {
            av[j] = *(const bf16x8*)(arow + (size_t)(kt0 + j) * 32);
            bv[j] = *(const bf16x8*)(brow + (size_t)(kt0 + j) * 32);
        }
        #pragma unroll
        for (int j = 0; j < 8; ++j)
            acc = __builtin_amdgcn_mfma_f32_16x16x32_bf16(av[j], bv[j], acc, 0, 0, 0);
    }
    const int col = col0 + ar;
    float bs = bias ? bias[col] : 0.f;
    float sc = scaleptr ? *scaleptr : 0.f;
    #pragma unroll
    for (int r = 0; r < 4; ++r) {
        int row = (lane >> 4) * 4 + r;
        float v = acc[r] + bs;
        if (pre) v += pre[(size_t)row * N + col];
        if (act == ACT_SILU)      v = v / (1.f + expf(-v));
        else if (act == ACT_TANH) v = tanhf(v);
        if (curf) {
            size_t o = (size_t)row * 512 + col;
            float nc = curf[o] - v * sc;
            curf[o] = nc;
            curb[o] = __float2bfloat16(nc);
        } else {
            size_t o = (size_t)z * oZ + (size_t)row * N + col;
            if (Of) Of[o] = v;
            if (Ob) Ob[o] = __float2bfloat16(v);
        }
    }
}

// ---------------- per-head squared norms from packed qkv (lda=1536) ----------------
__global__ __launch_bounds__(256) void sqnorm2_kernel(const bh16* __restrict__ qkv,
                                                      float* __restrict__ qn, float* __restrict__ kn)
{
    int lane = threadIdx.x & 63, wid = threadIdx.x >> 6;
    int row = blockIdx.x * 4 + wid;            // over B*H*T
    const bh16* src = qkv + (blockIdx.y ? 512 : 0);
    float* dst = blockIdx.y ? kn : qn;
    int t = row & 255; int bh = row >> 8; int b = bh >> 3, hh = bh & 7;
    float v = __bfloat162float(src[((size_t)b * TT + t) * 1536 + hh * 64 + lane]);
    float s = v * v;
    #pragma unroll
    for (int off = 32; off; off >>= 1) s += __shfl_xor(s, off);
    if (lane == 0) dst[row] = s;
}

// ---------------- hyperbolic distance + softmax: fp32 logits in, bf16 probs out ----------------
__global__ __launch_bounds__(256) void attn_softmax_kernel(const float* __restrict__ at, bh16* __restrict__ pb,
                                                           const float* __restrict__ qn,
                                                           const float* __restrict__ kn,
                                                           const float* __restrict__ curv)
{
    int lane = threadIdx.x & 63, wid = threadIdx.x >> 6;
    int row = blockIdx.x * 4 + wid;            // over B*H*T
    int i = row & 255; int bh = row >> 8; int hh = bh & 7;
    float c = fabsf(curv[hh]) + 1e-8f;
    float inv_sqrt_c = 1.f / sqrtf(c);
    float qni = qn[row];
    const float* srow = at + (size_t)bh * TT * TT + (size_t)i * TT;
    bh16* prow = pb + (size_t)bh * TT * TT + (size_t)i * TT;
    const float* knr = kn + (size_t)bh * TT;
    float logit[4];
    float mx = -1e30f;
    #pragma unroll
    for (int u = 0; u < 4; ++u) {
        int j = lane + u * 64;
        float s = srow[j];
        float knj = knr[j];
        float d2 = fmaxf(qni + knj - 2.f * s, 0.f);
        float denom = fmaxf((1.f - c * qni) * (1.f - c * knj), 1e-5f);
        float arg = fmaxf(1.f + (2.f * c * d2) / denom, 1.00001f);
        float dist = logf(arg + sqrtf((arg - 1.f) * (arg + 1.f))) * inv_sqrt_c;
        logit[u] = -dist;
        mx = fmaxf(mx, logit[u]);
    }
    #pragma unroll
    for (int off = 32; off; off >>= 1) mx = fmaxf(mx, __shfl_xor(mx, off));
    float e[4]; float sum = 0.f;
    #pragma unroll
    for (int u = 0; u < 4; ++u) { e[u] = expf(logit[u] - mx); sum += e[u]; }
    #pragma unroll
    for (int off = 32; off; off >>= 1) sum += __shfl_xor(sum, off);
    float inv = 1.f / sum;
    #pragma unroll
    for (int u = 0; u < 4; ++u) prow[lane + u * 64] = __float2bfloat16(e[u] * inv);
}

// ---------------- V transpose per (b,h): packed qkv (v at +1024, lda=1536) -> vt[bh][d][t] ----------------
__global__ __launch_bounds__(256) void vtrans_kernel(const bh16* __restrict__ vb, bh16* __restrict__ vt)
{
    int bh = blockIdx.y, b = bh >> 3, hh = bh & 7;
    int t0 = blockIdx.x * 64;
    __shared__ bh16 tile[64][65];
    for (int e = threadIdx.x; e < 4096; e += 256) {
        int r = e >> 6, c = e & 63;
        tile[r][c] = vb[((size_t)(b*256 + t0 + r))*1536 + hh*64 + c];
    }
    __syncthreads();
    for (int e = threadIdx.x; e < 4096; e += 256) {
        int d = e >> 6, t2 = e & 63;
        vt[((size_t)bh*64 + d)*256 + t0 + t2] = tile[t2][d];
    }
}

// ---------------- wavelet filter softmax ----------------
__global__ __launch_bounds__(256) void filt_softmax_kernel(const float* __restrict__ w0, const float* __restrict__ w1,
                                                           const float* __restrict__ w2, const float* __restrict__ w3,
                                                           float* __restrict__ filt)
{
    int idx = blockIdx.x * 256 + threadIdx.x;
    if (idx >= 4 * DD) return;
    int d = idx & 511, i = idx >> 9;
    const float* w = (i == 0) ? w0 : (i == 1) ? w1 : (i == 2) ? w2 : w3;
    int K = 4 << i;
    int fb = (i == 0) ? 0 : (i == 1) ? 2048 : (i == 2) ? 6144 : 14336;
    const float* row = w + (size_t)d * K;
    float mx = -1e30f;
    for (int k = 0; k < K; ++k) mx = fmaxf(mx, row[k]);
    float s = 0.f;
    for (int k = 0; k < K; ++k) s += expf(row[k] - mx);
    float inv = 1.f / s;
    float* fo = filt + fb + (size_t)d * K;
    for (int k = 0; k < K; ++k) fo[k] = expf(row[k] - mx) * inv;
}

// ---------------- all 4 wavelet decompositions fused ----------------
__global__ __launch_bounds__(256) void wdec_kernel(const float* __restrict__ h, const float* __restrict__ filt,
                                                   float* __restrict__ dec)
{
    int idx = blockIdx.x * 256 + threadIdx.x;   // < 1966080
    int i, base;
    if (idx < 1048576)      { i = 0; base = 0; }
    else if (idx < 1572864) { i = 1; base = 1048576; }
    else if (idx < 1835008) { i = 2; base = 1572864; }
    else                    { i = 3; base = 1835008; }
    int loc = idx - base;
    int K = 4 << i, stride = 2 << i, lgTi = 7 - i, Ti = 128 >> i;
    const int fbarr[4] = {0, 2048, 6144, 14336};
    int d = loc & 511; int rem = loc >> 9; int j = rem & (Ti - 1); int b = rem >> lgTi;
    const float* frow = filt + fbarr[i] + (size_t)d * K;
    int tbase = j * stride - (K - 1);
    float acc = 0.f;
    for (int k = 0; k < K; ++k) {
        int t = tbase + k;
        if (t >= 0) acc += h[((size_t)b * TT + t) * DD + d] * frow[k];
    }
    dec[idx] = acc;
}

// ---------------- linear interp back to T: comb (B,T,4D) bf16 ----------------
__global__ __launch_bounds__(256) void winterp_kernel(const float* __restrict__ dec, bh16* __restrict__ comb)
{
    int idx = blockIdx.x * 256 + threadIdx.x;   // over B*T*2048
    int col = idx & 2047; int rem = idx >> 11; int t = rem & 255; int b = rem >> 8;
    if (b >= BB) return;
    int i = col >> 9, d = col & 511;
    int Ti = 256 >> (i + 1);
    const size_t offs[4] = {0, 1048576, 1572864, 1835008};
    float pos = ((float)t + 0.5f) * ((float)Ti / 256.f) - 0.5f;
    pos = fminf(fmaxf(pos, 0.f), (float)(Ti - 1));
    int lo = (int)floorf(pos);
    int hi = min(lo + 1, Ti - 1);
    float w = pos - (float)lo;
    const float* db = dec + offs[i] + (size_t)b * Ti * DD;
    float vlo = db[(size_t)lo * DD + d], vhi = db[(size_t)hi * DD + d];
    comb[idx] = __float2bfloat16(vlo * (1.f - w) + vhi * w);
}

// ---------------- boundary loss: 32 blocks, one atomic per block ----------------
__global__ __launch_bounds__(256) void bd_loss_kernel(const float* __restrict__ tfb, const float* __restrict__ bdw,
                                                      const float* __restrict__ bdb, float* __restrict__ loss)
{
    __shared__ float wsum[4];
    int lane = threadIdx.x & 63, wid = threadIdx.x >> 6;
    float w = bdw[lane * 2] - bdw[lane * 2 + 1];
    float bconst = (bdb[0] - bdb[1]) + 0.1f;
    float acc = 0.f;
    for (int row = blockIdx.x * 4 + wid; row < BT; row += 128) {
        float vv = tfb[(size_t)row * PP + lane] * w;
        #pragma unroll
        for (int off = 32; off; off >>= 1) vv += __shfl_xor(vv, off);
        if (lane == 0) acc += fmaxf(vv + bconst, 0.f);
    }
    if (lane == 0) wsum[wid] = acc;
    __syncthreads();
    if (threadIdx.x == 0) {
        atomicAdd(loss, (wsum[0] + wsum[1] + wsum[2] + wsum[3]) * (1.f / 4096.f));
    }
}

// ---------------- h = layernorm(s + h)*g + b, dual fp32+bf16 out ----------------
__global__ __launch_bounds__(256) void add_ln_kernel(const float* __restrict__ s, float* __restrict__ h,
                                                     bh16* __restrict__ hb,
                                                     const float* __restrict__ g, const float* __restrict__ be)
{
    int lane = threadIdx.x & 63, wid = threadIdx.x >> 6;
    size_t row = (size_t)blockIdx.x * 4 + wid;
    const float* sr = s + row * DD;
    float* hr = h + row * DD;
    bh16* hbr = hb + row * DD;
    float xv[8]; float sum = 0.f;
    #pragma unroll
    for (int u = 0; u < 8; ++u) { int c = lane + u * 64; xv[u] = sr[c] + hr[c]; sum += xv[u]; }
    #pragma unroll
    for (int off = 32; off; off >>= 1) sum += __shfl_xor(sum, off);
    float mu = sum * (1.f / 512.f);
    float sq = 0.f;
    #pragma unroll
    for (int u = 0; u < 8; ++u) { float d = xv[u] - mu; sq += d * d; }
    #pragma unroll
    for (int off = 32; off; off >>= 1) sq += __shfl_xor(sq, off);
    float rstd = 1.f / sqrtf(sq * (1.f / 512.f) + 1e-5f);
    #pragma unroll
    for (int u = 0; u < 8; ++u) {
        int c = lane + u * 64;
        float v = (xv[u] - mu) * rstd * g[c] + be[c];
        hr[c] = v;
        hbr[c] = __float2bfloat16(v);
    }
}

// ---------------- weight transpose-convert: [l-sel][K][N] f32 -> out + l*lstride, [N][K] bf16 ----------------
__global__ __launch_bounds__(256) void wtrans_kernel(const float* __restrict__ W, bh16* __restrict__ Wt,
                                                     int K, int N, long lstride)
{
    int l = blockIdx.z;
    const float* Wl = W + (size_t)l * K * N;
    bh16* Wo = Wt + (size_t)l * lstride;
    __shared__ float tile[32][33];
    int n0 = blockIdx.x * 32, k0 = blockIdx.y * 32;
    int lx = threadIdx.x & 31, ly = threadIdx.x >> 5;
    #pragma unroll
    for (int j = 0; j < 4; ++j) {
        int kk = ly + j * 8;
        tile[kk][lx] = Wl[(size_t)(k0 + kk) * N + n0 + lx];
    }
    __syncthreads();
    #pragma unroll
    for (int j = 0; j < 4; ++j) {
        int nr = ly + j * 8;
        Wo[(size_t)(n0 + nr) * K + k0 + lx] = __float2bfloat16(tile[lx][nr]);
    }
}

// ---------------- cc_w [L][O][I][3] f32 -> ccT [L][O][tap*512+I] bf16 (tap-major K for fused conv GEMM) ----------------
__global__ __launch_bounds__(256) void ccconv_kernel(const float* __restrict__ ccw, bh16* __restrict__ ccT)
{
    size_t idx = (size_t)blockIdx.x * 256 + threadIdx.x;   // 6*512*1536
    int i = idx & 511; size_t rem = idx >> 9;
    int tap = (int)(rem % 3); rem /= 3;
    int o = (int)(rem & 511); int l = (int)(rem >> 9);
    ccT[idx] = __float2bfloat16(ccw[(((size_t)l*512 + o)*512 + i)*3 + tap]);
}

// ---------------- qkv bias concat: [L][1536] ----------------
__global__ __launch_bounds__(256) void qkvbias_kernel(const float* __restrict__ qb_, const float* __restrict__ kb_,
                                                      const float* __restrict__ vb_, float* __restrict__ ob)
{
    int idx = blockIdx.x * 256 + threadIdx.x;   // 6*1536
    if (idx >= 6 * 1536) return;
    int l = idx / 1536, n = idx % 1536;
    float v = (n < 512) ? qb_[l*512 + n] : (n < 1024) ? kb_[l*512 + n - 512] : vb_[l*512 + n - 1024];
    ob[idx] = v;
}

// ---------------- x f32 -> bf16 ----------------
__global__ __launch_bounds__(256) void convx_kernel(const float* __restrict__ x, bh16* __restrict__ xb)
{
    size_t idx = (size_t)blockIdx.x * 256 + threadIdx.x;
    xb[idx] = __float2bfloat16(x[idx]);
}

// ---------------- E matrix: row (t,b) = [sched[t]*noise[t,b,:] | temb[t]] (bf16, 160x1024) ----------------
__global__ __launch_bounds__(256) void build_E_kernel(const float* __restrict__ noise, const float* __restrict__ sched,
                                                      bh16* __restrict__ E)
{
    int idx = blockIdx.x * 256 + threadIdx.x;   // 10*16*1024
    if (idx >= SS * BB * 1024) return;
    int k = idx & 1023; int rem = idx >> 10; int b = rem & 15; int t = rem >> 4;
    float v;
    if (k < 512) {
        v = sched[t] * noise[((size_t)t * BB + b) * 512 + k];
    } else {
        int j = k - 512;
        const float kfac = -9.210340371976184f / 255.f;   // -ln(10000)/255
        v = (j < 256) ? sinf((float)t * expf((float)j * kfac))
                      : cosf((float)t * expf((float)(j - 256) * kfac));
    }
    E[idx] = __float2bfloat16(v);
}

// ---------------- head helpers ----------------
__global__ void init_kernel(bh16* zp, float* loss)
{
    int t = threadIdx.x;
    if (t < 64) zp[t] = __float2bfloat16(0.f);
    if (t == 64) *loss = 0.f;
}

__global__ __launch_bounds__(256) void build_cat16_kernel(const float* __restrict__ h, bh16* __restrict__ catb)
{
    int idx = blockIdx.x * 256 + threadIdx.x;   // 16*1024
    if (idx >= BB * 1024) return;
    int k = idx & 1023, b = idx >> 10;
    float v = (k < 512) ? h[((size_t)b * TT + 255) * DD + k]
                        : h[((size_t)b * TT + 254) * DD + (k - 512)];
    catb[idx] = __float2bfloat16(v);
}

__global__ __launch_bounds__(256) void cur_init2_kernel(const float* __restrict__ h, const float* __restrict__ mix,
                                                        float* __restrict__ curf, bh16* __restrict__ curb)
{
    int idx = blockIdx.x * 256 + threadIdx.x;   // 16*512
    if (idx >= BB * DD) return;
    int c = idx & 511, b = idx >> 9;
    float v = h[((size_t)b * TT + 255) * DD + c] + mix[idx];
    curf[idx] = v;
    curb[idx] = __float2bfloat16(v);
}

__global__ void fail_kernel(float* p) { p[0] = 1e30f; }

// =====================================================================================
extern "C" void kernel_launch(void* const* d_in, const int* in_sizes, int n_in,
                              void* d_out, int out_size, void* d_ws, size_t ws_size,
                              hipStream_t stream)
{
    const float* x      = (const float*)d_in[0];
    const float* in_w   = (const float*)d_in[1];
    const float* in_b   = (const float*)d_in[2];
    const float* gq_w   = (const float*)d_in[3];
    const float* gq_b   = (const float*)d_in[4];
    const float* gk_w   = (const float*)d_in[5];
    const float* gk_b   = (const float*)d_in[6];
    const float* gv_w   = (const float*)d_in[7];
    const float* gv_b   = (const float*)d_in[8];
    const float* go_w   = (const float*)d_in[9];
    const float* go_b   = (const float*)d_in[10];
    const float* curv   = (const float*)d_in[11];
    const float* wav0   = (const float*)d_in[12];
    const float* wav1   = (const float*)d_in[13];
    const float* wav2   = (const float*)d_in[14];
    const float* wav3   = (const float*)d_in[15];
    const float* wrec_w = (const float*)d_in[16];
    const float* wrec_b = (const float*)d_in[17];
    const float* te1_w  = (const float*)d_in[18];
    const float* te1_b  = (const float*)d_in[19];
    const float* te2_w  = (const float*)d_in[20];
    const float* te2_b  = (const float*)d_in[21];
    const float* td1_w  = (const float*)d_in[22];
    const float* td1_b  = (const float*)d_in[23];
    const float* td2_w  = (const float*)d_in[24];
    const float* td2_b  = (const float*)d_in[25];
    const float* bd_w   = (const float*)d_in[26];
    const float* bd_b   = (const float*)d_in[27];
    const float* cc_w   = (const float*)d_in[28];
    const float* cc_b   = (const float*)d_in[29];
    const float* ln_g   = (const float*)d_in[30];
    const float* ln_b   = (const float*)d_in[31];
    const float* mm1_w  = (const float*)d_in[32];
    const float* mm1_b  = (const float*)d_in[33];
    const float* mm2_w  = (const float*)d_in[34];
    const float* mm2_b  = (const float*)d_in[35];
    const float* dn1_w  = (const float*)d_in[36];
    const float* dn1_b  = (const float*)d_in[37];
    const float* dn2_w  = (const float*)d_in[38];
    const float* dn2_b  = (const float*)d_in[39];
    const float* dn3_w  = (const float*)d_in[40];
    const float* dn3_b  = (const float*)d_in[41];
    const float* out_w  = (const float*)d_in[42];
    const float* out_b  = (const float*)d_in[43];
    const float* nsched = (const float*)d_in[44];
    const float* noise  = (const float*)d_in[45];
    float* out = (float*)d_out;
    float* ws  = (float*)d_ws;

    // ---- fp32 workspace layout (float offsets) ----
    const size_t o_h   = 0;          // 2097152
    const size_t o_dec = 2097152;    // 2097152 (also pre1 for head: 81920)
    const size_t o_s   = 4194304;    // 2097152
    const size_t o_tf  = 6291456;    // 262144
    const size_t o_qn  = 6553600;    // 32768
    const size_t o_kn  = 6586368;    // 32768
    const size_t o_at  = 6619136;    // 8388608
    const size_t o_fl  = 15007744;   // 30720
    const size_t o_mix = 15038464;   // 8192
    const size_t o_cur = 15046656;   // 8192
    const size_t o_qkb = 15054848;   // 9216 (qkv bias [6][1536])
    const size_t FP32_TOTAL = 15095808;
    // ---- bf16 region (element offsets from bp) ----
    const size_t b_xb   = 0;          // 1572864
    const size_t b_hb   = 1572864;    // 2097152
    const size_t b_qkv  = 3670016;    // 6291456: packed qkv [4096][1536]
    const size_t b_vt   = 9961472;    // 2097152
    const size_t b_pb   = 12058624;   // 8388608 (head scratch aliases here after layers)
    const size_t b_gmb  = 20447232;   // 2097152
    const size_t b_tdb  = 22544384;   // 2097152
    const size_t b_t1b  = 24641536;   // 262144
    const size_t b_tfb  = 24903680;   // 262144
    const size_t b_zp   = 25165824;   // 512
    const size_t b_inwT = 25166336;   // 196608
    const size_t b_qkvT = 25362944;   // 4718592: [6][1536][512]
    const size_t b_goT  = 30081536;   // 1572864
    const size_t b_wrT  = 31654400;   // 6291456
    const size_t b_td1T = 37945856;   // 196608
    const size_t b_td2T = 38142464;   // 1572864
    const size_t b_te1T = 39715328;   // 196608
    const size_t b_te2T = 39911936;   // 24576
    const size_t b_ccT  = 39936512;   // 4718592: [6][512][1536]
    const size_t BF16_TOTAL = 44655104;
    const size_t TOTAL_BYTES = FP32_TOTAL * 4 + BF16_TOTAL * 2;
    if (ws_size < TOTAL_BYTES) { fail_kernel<<<1, 1, 0, stream>>>(out); return; }

    float* h_   = ws + o_h;
    float* dec_ = ws + o_dec;
    float* s_   = ws + o_s;
    float* tf_  = ws + o_tf;
    float* qn_  = ws + o_qn;
    float* kn_  = ws + o_kn;
    float* at_  = ws + o_at;
    float* fl_  = ws + o_fl;
    float* mixb = ws + o_mix;
    float* curf = ws + o_cur;
    float* qkvbias = ws + o_qkb;
    bh16* bp   = (bh16*)(ws + FP32_TOTAL);
    bh16* xb   = bp + b_xb;
    bh16* hb   = bp + b_hb;
    bh16* qkvb = bp + b_qkv;
    bh16* vt   = bp + b_vt;
    bh16* pb   = bp + b_pb;
    bh16* gmb  = bp + b_gmb;
    bh16* tdb  = bp + b_tdb;
    bh16* t1b  = bp + b_t1b;
    bh16* tfb  = bp + b_tfb;
    bh16* zp   = bp + b_zp;
    bh16* inwT = bp + b_inwT;
    bh16* qkvT = bp + b_qkvT;
    bh16* goT  = bp + b_goT;
    bh16* wrT  = bp + b_wrT;
    bh16* td1T = bp + b_td1T;
    bh16* td2T = bp + b_td2T;
    bh16* te1T = bp + b_te1T;
    bh16* te2T = bp + b_te2T;
    bh16* ccT  = bp + b_ccT;
    bh16* combb = (bh16*)at_;   // aliases at_ after softmax consumed it

    // head bf16 scratch: aliased into pb region (dead after layer loop)
    bh16* dn1T  = pb;             // 524288
    bh16* dn2T  = pb + 524288;    // 262144
    bh16* dn3T  = pb + 786432;    // 262144
    bh16* mm1T  = pb + 1048576;   // 524288
    bh16* mm2T  = pb + 1572864;   // 262144
    bh16* outT  = pb + 1835008;   // 196608
    bh16* E16   = pb + 2031616;   // 163840
    bh16* cat16 = pb + 2195456;   // 16384
    bh16* tmb16 = pb + 2211840;   // 8192
    bh16* cur16 = pb + 2220032;   // 8192
    bh16* d1b16 = pb + 2228224;   // 8192
    bh16* d2b16 = pb + 2236416;   // 8192
    float* pre1 = dec_;           // 81920 f32, aliases dec_ after layers

    auto mg = [&](const bh16* A, int lda, const bh16* Bt, int ldb,
                  const float* bias, float* Cf, bh16* Cb, int ldc,
                  int M, int N, int K, int shift, int accum, int act,
                  int nb, int zmask, int zshift,
                  long aS1, long aS0, long bS1, long bS0, long cS1, long cS0, int ccdil) {
        dim3 g(N / 64, M / 128, nb);
        mgemm_kernel<<<g, 256, 0, stream>>>(A, lda, Bt, ldb, bias, Cf, Cb, ldc, N, K,
                                            shift, accum, act, zmask, zshift,
                                            aS1, aS0, bS1, bS0, cS1, cS0, ccdil, zp);
    };
    auto mgp = [&](const bh16* A, int lda, const bh16* Bt, int ldb,
                   const float* bias, float* Cf, bh16* Cb, int ldc,
                   int M, int N, int K, int shift, int accum, int act) {
        mg(A, lda, Bt, ldb, bias, Cf, Cb, ldc, M, N, K, shift, accum, act, 1, 0, 0, 0, 0, 0, 0, 0, 0, 0);
    };
    auto hg = [&](const bh16* A, int lda, long aZ, const bh16* Bt, int ldb,
                  const float* bias, const float* pre, float* Of, bh16* Ob, long oZ,
                  int N, int K, int act, float* cf, bh16* cb, const float* sp, int nz) {
        hgemm16_kernel<<<dim3(N / 64, 1, nz), 256, 0, stream>>>(
            A, lda, aZ, Bt, ldb, bias, pre, Of, Ob, oZ, N, K, act, cf, cb, sp);
    };

    // ---- setup: zero page/loss, converts ----
    init_kernel<<<1, 128, 0, stream>>>(zp, out + BB * DIN);
    convx_kernel<<<BT * DIN / 256, 256, 0, stream>>>(x, xb);
    wtrans_kernel<<<dim3(DD/32, DIN/32, 1), 256, 0, stream>>>(in_w, inwT, DIN, DD, (long)DIN*DD);
    // packed qkvT: rows 0-511 q, 512-1023 k, 1024-1535 v; l-stride 786432
    wtrans_kernel<<<dim3(16, 16, 6), 256, 0, stream>>>(gq_w, qkvT,          DD, DD, 786432L);
    wtrans_kernel<<<dim3(16, 16, 6), 256, 0, stream>>>(gk_w, qkvT + 262144, DD, DD, 786432L);
    wtrans_kernel<<<dim3(16, 16, 6), 256, 0, stream>>>(gv_w, qkvT + 524288, DD, DD, 786432L);
    qkvbias_kernel<<<36, 256, 0, stream>>>(gq_b, gk_b, gv_b, qkvbias);
    wtrans_kernel<<<dim3(16, 16, 6), 256, 0, stream>>>(go_w, goT, DD, DD, (long)DD*DD);
    wtrans_kernel<<<dim3(16, 64, 6), 256, 0, stream>>>(wrec_w, wrT, 2048, DD, 2048L*DD);
    wtrans_kernel<<<dim3(16, 2, 6), 256, 0, stream>>>(td1_w, td1T, PP, DD, (long)PP*DD);
    wtrans_kernel<<<dim3(16, 16, 6), 256, 0, stream>>>(td2_w, td2T, DD, DD, (long)DD*DD);
    wtrans_kernel<<<dim3(2, 16, 6), 256, 0, stream>>>(te1_w, te1T, DD, PP, (long)DD*PP);
    wtrans_kernel<<<dim3(2, 2, 6), 256, 0, stream>>>(te2_w, te2T, PP, PP, (long)PP*PP);
    ccconv_kernel<<<18432, 256, 0, stream>>>(cc_w, ccT);

    // h = x @ in_w + in_b  (fp32 + bf16)
    mgp(xb, DIN, inwT, DIN, in_b, h_, hb, DD, BT, DD, DIN, 0, 0, ACT_NONE);

    for (int l = 0; l < LL; ++l) {
        // fused q|k|v projection: N=1536, packed output [BT][1536]
        mgp(hb, DD, qkvT + (size_t)l*786432, DD, qkvbias + (size_t)l*1536,
            nullptr, qkvb, 1536, BT, 1536, DD, 0, 0, ACT_NONE);
        // attention
        sqnorm2_kernel<<<dim3(8192, 2), 256, 0, stream>>>(qkvb, qn_, kn_);
        mg(qkvb, 1536, qkvb + 512, 1536, nullptr, at_, nullptr, TT, TT, TT, 64, 0, 0, ACT_NONE,
           128, 7, 3, 393216, 64, 393216, 64, 524288, 65536, 0);
        attn_softmax_kernel<<<8192, 256, 0, stream>>>(at_, pb, qn_, kn_, curv + (size_t)l*HH);
        vtrans_kernel<<<dim3(4, 128), 256, 0, stream>>>(qkvb + 1024, vt);
        mg(pb, TT, vt, TT, nullptr, nullptr, gmb, DD, TT, 64, TT, 0, 0, ACT_NONE,
           128, 7, 3, 524288, 65536, 131072, 16384, 131072, 64, 0);
        mgp(gmb, DD, goT + (size_t)l*262144, DD, go_b + (size_t)l*DD, s_, nullptr, DD, BT, DD, DD, 0, 0, ACT_NONE);
        // wavelet branch
        filt_softmax_kernel<<<8, 256, 0, stream>>>(wav0 + (size_t)l*DD*4, wav1 + (size_t)l*DD*8,
                                                   wav2 + (size_t)l*DD*16, wav3 + (size_t)l*DD*32, fl_);
        wdec_kernel<<<7680, 256, 0, stream>>>(h_, fl_, dec_);
        winterp_kernel<<<(BT * 2048) / 256, 256, 0, stream>>>(dec_, combb);
        mgp(combb, 2048, wrT + (size_t)l*1048576, 2048, wrec_b + (size_t)l*DD, s_, nullptr, DD, BT, DD, 2048, 0, 1, ACT_NONE);
        // topo branch
        mgp(hb, DD, te1T + (size_t)l*32768, DD, te1_b + (size_t)l*PP, nullptr, t1b, PP, BT, PP, DD, 0, 0, ACT_RELU);
        mgp(t1b, PP, te2T + (size_t)l*4096, PP, te2_b + (size_t)l*PP, tf_, tfb, PP, BT, PP, PP, 0, 0, ACT_NONE);
        bd_loss_kernel<<<32, 256, 0, stream>>>(tf_, bd_w + (size_t)l*PP*2, bd_b + (size_t)l*2, out + BB*DIN);
        mgp(tfb, PP, td1T + (size_t)l*32768, PP, td1_b + (size_t)l*DD, nullptr, tdb, DD, BT, DD, PP, 0, 0, ACT_RELU);
        mgp(tdb, DD, td2T + (size_t)l*262144, DD, td2_b + (size_t)l*DD, s_, nullptr, DD, BT, DD, DD, 0, 1, ACT_NONE);
        // fused causal dilated conv: single K=1536 GEMM, per-K-tile shift schedule
        int dil = 1 << l;
        mg(hb, DD, ccT + (size_t)l*786432, 1536, cc_b + (size_t)l*DD,
           s_, nullptr, DD, BT, DD, 1536, 0, 1, ACT_NONE, 1, 0, 0, 0, 0, 0, 0, 0, 0, dil);
        // h = LN(s + h)
        add_ln_kernel<<<BT/4, 256, 0, stream>>>(s_, h_, hb, ln_g, ln_b);
    }

    // ---- head: convert weights (into dead pb region), precompute E/pre1 ----
    wtrans_kernel<<<dim3(16, 32, 1), 256, 0, stream>>>(dn1_w, dn1T, 1024, 512, 0L);
    wtrans_kernel<<<dim3(16, 16, 1), 256, 0, stream>>>(dn2_w, dn2T, 512, 512, 0L);
    wtrans_kernel<<<dim3(16, 16, 1), 256, 0, stream>>>(dn3_w, dn3T, 512, 512, 0L);
    wtrans_kernel<<<dim3(16, 32, 1), 256, 0, stream>>>(mm1_w, mm1T, 1024, 512, 0L);
    wtrans_kernel<<<dim3(16, 16, 1), 256, 0, stream>>>(mm2_w, mm2T, 512, 512, 0L);
    wtrans_kernel<<<dim3(12, 16, 1), 256, 0, stream>>>(out_w, outT, 512, 384, 0L);
    build_E_kernel<<<640, 256, 0, stream>>>(noise, nsched, E16);
    // pre1[t] = E_t @ dn1_w + dn1_b   (z-batched over t)
    hg(E16, 1024, 16*1024, dn1T, 1024, dn1_b, nullptr, pre1, nullptr, 8192,
       512, 1024, ACT_NONE, nullptr, nullptr, nullptr, SS);
    // mix head
    build_cat16_kernel<<<64, 256, 0, stream>>>(h_, cat16);
    hg(cat16, 1024, 0, mm1T, 1024, mm1_b, nullptr, nullptr, tmb16, 0,
       512, 1024, ACT_TANH, nullptr, nullptr, nullptr, 1);
    hg(tmb16, 512, 0, mm2T, 512, mm2_b, nullptr, mixb, nullptr, 0,
       512, 512, ACT_NONE, nullptr, nullptr, nullptr, 1);
    cur_init2_kernel<<<32, 256, 0, stream>>>(h_, mixb, curf, cur16);
    // diffusion chain: 3 launches per step
    for (int t = 0; t < SS; ++t) {
        hg(cur16, 512, 0, dn1T, 1024, nullptr, pre1 + (size_t)t*8192, nullptr, d1b16, 0,
           512, 512, ACT_SILU, nullptr, nullptr, nullptr, 1);
        hg(d1b16, 512, 0, dn2T, 512, dn2_b, nullptr, nullptr, d2b16, 0,
           512, 512, ACT_SILU, nullptr, nullptr, nullptr, 1);
        hg(d2b16, 512, 0, dn3T, 512, dn3_b, nullptr, nullptr, nullptr, 0,
           512, 512, ACT_NONE, curf, cur16, nsched + t, 1);
    }
    // pred = cur @ out_w + out_b
    hg(cur16, 512, 0, outT, 512, out_b, nullptr, out, nullptr, 0,
       384, 512, ACT_NONE, nullptr, nullptr, nullptr, 1);
}